// Round 2
// baseline (127.247 us; speedup 1.0000x reference)
//
#include <hip/hip_runtime.h>
#include <hip/hip_bf16.h>

#define SCALE_2LOG2E 2.8853900817779268f   // 2*log2(e): folded into projections
#define LOG2E 1.4426950408889634f

#define NB 8
#define TQ 32
#define TK 2048
#define DD 256

// ---------------------------------------------------------------------------
// K1: projection GEMM  C[m][u] = SCALE * sum_d A[m][d] * W[u][d]
// 128x128 tile, 256 threads, 8x8 micro-tile (1B LDS traffic per FMA).
// LDS layout k-major with XOR swizzle: F(k,row) = k*128 + (row ^ 8*((k>>2)&3))
//   - staging writes: 2-way bank aliasing (free)
//   - A reads: 4 unique addrs/wave (broadcast), W reads: 16 unique (mild 4-way)
// Register prefetch of next K-tile hides global latency under 64-FMA inner loop.
// blockIdx.x < 128: keys*Wk^T -> kp ; else: query*Wq^T -> qp.
// ---------------------------------------------------------------------------
__global__ __launch_bounds__(256) void proj_gemm(const float* __restrict__ keys,
                                                 const float* __restrict__ Wk,
                                                 float* __restrict__ kpo,
                                                 const float* __restrict__ query,
                                                 const float* __restrict__ Wq,
                                                 float* __restrict__ qpo) {
  __shared__ float As[32 * 128];
  __shared__ float Ws[32 * 128];
  const int tid = threadIdx.x;
  const float* A; const float* W; float* C; int m0;
  if (blockIdx.x < 128) {
    A = keys; W = Wk; C = kpo; m0 = blockIdx.x * 128;
  } else {
    A = query; W = Wq; C = qpo; m0 = ((int)blockIdx.x - 128) * 128;
  }
  const int n0 = blockIdx.y * 128;
  const int tm = tid >> 4, tn = tid & 15;

  float4 pa[4], pw[4];
#pragma unroll
  for (int r = 0; r < 4; ++r) {
    int idx = tid + r * 256, row = idx >> 3, c4 = idx & 7;
    pa[r] = *(const float4*)(A + (m0 + row) * 256 + c4 * 4);
    pw[r] = *(const float4*)(W + (n0 + row) * 256 + c4 * 4);
  }
  float acc[8][8] = {};

  for (int k0 = 0; k0 < 256; k0 += 32) {
#pragma unroll
    for (int r = 0; r < 4; ++r) {
      int idx = tid + r * 256, row = idx >> 3, c4 = idx & 7;
      int swr = row ^ ((c4 & 3) << 3);
      As[(c4 * 4 + 0) * 128 + swr] = pa[r].x;
      As[(c4 * 4 + 1) * 128 + swr] = pa[r].y;
      As[(c4 * 4 + 2) * 128 + swr] = pa[r].z;
      As[(c4 * 4 + 3) * 128 + swr] = pa[r].w;
      Ws[(c4 * 4 + 0) * 128 + swr] = pw[r].x;
      Ws[(c4 * 4 + 1) * 128 + swr] = pw[r].y;
      Ws[(c4 * 4 + 2) * 128 + swr] = pw[r].z;
      Ws[(c4 * 4 + 3) * 128 + swr] = pw[r].w;
    }
    __syncthreads();
    if (k0 + 32 < 256) {
#pragma unroll
      for (int r = 0; r < 4; ++r) {
        int idx = tid + r * 256, row = idx >> 3, c4 = idx & 7;
        pa[r] = *(const float4*)(A + (m0 + row) * 256 + k0 + 32 + c4 * 4);
        pw[r] = *(const float4*)(W + (n0 + row) * 256 + k0 + 32 + c4 * 4);
      }
    }
#pragma unroll
    for (int kk = 0; kk < 32; ++kk) {
      const int s = (kk >> 2) & 3;
      const float4 a0 = *(const float4*)&As[kk * 128 + ((tm ^ s) << 3)];
      const float4 a1 = *(const float4*)&As[kk * 128 + ((tm ^ s) << 3) + 4];
      const float4 w0 = *(const float4*)&Ws[kk * 128 + ((tn ^ s) << 3)];
      const float4 w1 = *(const float4*)&Ws[kk * 128 + ((tn ^ s) << 3) + 4];
      const float av[8] = {a0.x, a0.y, a0.z, a0.w, a1.x, a1.y, a1.z, a1.w};
      const float wv8[8] = {w0.x, w0.y, w0.z, w0.w, w1.x, w1.y, w1.z, w1.w};
#pragma unroll
      for (int i = 0; i < 8; ++i)
#pragma unroll
        for (int j = 0; j < 8; ++j)
          acc[i][j] = fmaf(av[i], wv8[j], acc[i][j]);
    }
    __syncthreads();
  }
#pragma unroll
  for (int i = 0; i < 8; ++i) {
    float* cr = C + (m0 + tm * 8 + i) * 256 + n0 + tn * 8;
    *(float4*)cr = make_float4(acc[i][0] * SCALE_2LOG2E, acc[i][1] * SCALE_2LOG2E,
                               acc[i][2] * SCALE_2LOG2E, acc[i][3] * SCALE_2LOG2E);
    *(float4*)(cr + 4) = make_float4(acc[i][4] * SCALE_2LOG2E, acc[i][5] * SCALE_2LOG2E,
                                     acc[i][6] * SCALE_2LOG2E, acc[i][7] * SCALE_2LOG2E);
  }
}

// ---------------------------------------------------------------------------
// K2: scores[b][q][k] = V0 - 2*sum_u v[u]/(exp2(qp'+kp')+1)
// grid (32 kchunks, 8 b), 1024 threads (16 waves -> 4/SIMD). Wave w handles
// q rows {2w, 2w+1} interleaved: kp LDS read shared by both rows.
// kp tile in 64KB LDS, float4-XOR swizzle. qp/v rows wave-uniform -> s_load.
// ---------------------------------------------------------------------------
__global__ __launch_bounds__(1024) void score_kernel(const float* __restrict__ kproj,
                                                     const float* __restrict__ qproj,
                                                     const float* __restrict__ v,
                                                     float* __restrict__ scores) {
  __shared__ float kp[64 * 256];       // 64 KB
  const int tid = threadIdx.x;
  const int b = blockIdx.y;
  const int kbase = blockIdx.x * 64;
#pragma unroll
  for (int i = 0; i < 4; ++i) {
    int idx4 = tid + i * 1024;         // 0..4095 float4s
    int kk = idx4 >> 6, u4 = idx4 & 63;
    float4 t = *(const float4*)(kproj + (b * TK + kbase + kk) * 256 + u4 * 4);
    *(float4*)&kp[kk * 256 + ((u4 ^ (kk & 7)) << 2)] = t;
  }
  const int lane = tid & 63;
  float vs = (v[lane] + v[lane + 64]) + (v[lane + 128] + v[lane + 192]);
#pragma unroll
  for (int off = 32; off; off >>= 1) vs += __shfl_xor(vs, off, 64);
  __syncthreads();

  const int wv = tid >> 6;             // 0..15, q rows {2wv, 2wv+1}
  const int xorv = lane & 7;
  const float* qr0 = qproj + (b * TQ + wv * 2) * 256;
  const float* qr1 = qr0 + 256;
  float sc0 = 0.f, sc1 = 0.f;
#pragma unroll 4
  for (int u4 = 0; u4 < 64; ++u4) {
    float4 kpv = *(const float4*)&kp[lane * 256 + ((u4 ^ xorv) << 2)];
    float4 qa = *(const float4*)(qr0 + u4 * 4);   // uniform -> s_load
    float4 qb = *(const float4*)(qr1 + u4 * 4);   // uniform -> s_load
    float4 vv = *(const float4*)(v + u4 * 4);     // uniform -> s_load
    sc0 = fmaf(vv.x, __builtin_amdgcn_rcpf(__builtin_amdgcn_exp2f(kpv.x + qa.x) + 1.f), sc0);
    sc1 = fmaf(vv.x, __builtin_amdgcn_rcpf(__builtin_amdgcn_exp2f(kpv.x + qb.x) + 1.f), sc1);
    sc0 = fmaf(vv.y, __builtin_amdgcn_rcpf(__builtin_amdgcn_exp2f(kpv.y + qa.y) + 1.f), sc0);
    sc1 = fmaf(vv.y, __builtin_amdgcn_rcpf(__builtin_amdgcn_exp2f(kpv.y + qb.y) + 1.f), sc1);
    sc0 = fmaf(vv.z, __builtin_amdgcn_rcpf(__builtin_amdgcn_exp2f(kpv.z + qa.z) + 1.f), sc0);
    sc1 = fmaf(vv.z, __builtin_amdgcn_rcpf(__builtin_amdgcn_exp2f(kpv.z + qb.z) + 1.f), sc1);
    sc0 = fmaf(vv.w, __builtin_amdgcn_rcpf(__builtin_amdgcn_exp2f(kpv.w + qa.w) + 1.f), sc0);
    sc1 = fmaf(vv.w, __builtin_amdgcn_rcpf(__builtin_amdgcn_exp2f(kpv.w + qb.w) + 1.f), sc1);
  }
  float* srow = scores + (b * TQ + wv * 2) * TK + kbase + lane;
  srow[0]  = fmaf(-2.f, sc0, vs);
  srow[TK] = fmaf(-2.f, sc1, vs);
}

// ---------------------------------------------------------------------------
// K3: row softmax over 2048. One block per (b,q) row, 256 threads x 8 elems.
// ---------------------------------------------------------------------------
__global__ __launch_bounds__(256) void softmax_kernel(const float* __restrict__ scores,
                                                      float* __restrict__ attn) {
  const int row = blockIdx.x;
  const int tid = threadIdx.x;
  const float4* s4 = (const float4*)(scores + row * TK);
  float4 x0 = s4[tid], x1 = s4[tid + 256];
  float m = fmaxf(fmaxf(fmaxf(x0.x, x0.y), fmaxf(x0.z, x0.w)),
                  fmaxf(fmaxf(x1.x, x1.y), fmaxf(x1.z, x1.w)));
#pragma unroll
  for (int off = 32; off; off >>= 1) m = fmaxf(m, __shfl_xor(m, off, 64));
  __shared__ float redm[4], reds[4];
  const int lane = tid & 63, wv = tid >> 6;
  if (lane == 0) redm[wv] = m;
  __syncthreads();
  m = fmaxf(fmaxf(redm[0], redm[1]), fmaxf(redm[2], redm[3]));
  float e0 = __builtin_amdgcn_exp2f((x0.x - m) * LOG2E);
  float e1 = __builtin_amdgcn_exp2f((x0.y - m) * LOG2E);
  float e2 = __builtin_amdgcn_exp2f((x0.z - m) * LOG2E);
  float e3 = __builtin_amdgcn_exp2f((x0.w - m) * LOG2E);
  float e4 = __builtin_amdgcn_exp2f((x1.x - m) * LOG2E);
  float e5 = __builtin_amdgcn_exp2f((x1.y - m) * LOG2E);
  float e6 = __builtin_amdgcn_exp2f((x1.z - m) * LOG2E);
  float e7 = __builtin_amdgcn_exp2f((x1.w - m) * LOG2E);
  float s = ((e0 + e1) + (e2 + e3)) + ((e4 + e5) + (e6 + e7));
#pragma unroll
  for (int off = 32; off; off >>= 1) s += __shfl_xor(s, off, 64);
  if (lane == 0) reds[wv] = s;
  __syncthreads();
  float total = (reds[0] + reds[1]) + (reds[2] + reds[3]);
  float inv = __builtin_amdgcn_rcpf(total);
  float4* o4 = (float4*)(attn + row * TK);
  o4[tid] = make_float4(e0 * inv, e1 * inv, e2 * inv, e3 * inv);
  o4[tid + 256] = make_float4(e4 * inv, e5 * inv, e6 * inv, e7 * inv);
}

// ---------------------------------------------------------------------------
// K4: context partials: part[b][kc][q][d] = sum_{k in chunk} attn[b][q][k]*keys[b][k][d]
// ---------------------------------------------------------------------------
__global__ __launch_bounds__(256) void ctx_partial(const float* __restrict__ keys,
                                                   const float* __restrict__ attn,
                                                   float* __restrict__ part) {
  const int b = blockIdx.y, kc = blockIdx.x;
  const int d = threadIdx.x;
  const int kbase = kc * 64;
  float kv[64];
#pragma unroll
  for (int k = 0; k < 64; ++k)
    kv[k] = keys[(b * TK + kbase + k) * 256 + d];
  float* pout = part + (b * 32 + kc) * 8192 + d;
#pragma unroll 1
  for (int q = 0; q < 32; ++q) {
    const float4* ar = (const float4*)(attn + (b * TQ + q) * TK + kbase);  // uniform
    float a0 = 0.f, a1 = 0.f, a2 = 0.f, a3 = 0.f;
#pragma unroll
    for (int k4 = 0; k4 < 16; ++k4) {
      float4 av = ar[k4];
      a0 = fmaf(av.x, kv[k4 * 4 + 0], a0);
      a1 = fmaf(av.y, kv[k4 * 4 + 1], a1);
      a2 = fmaf(av.z, kv[k4 * 4 + 2], a2);
      a3 = fmaf(av.w, kv[k4 * 4 + 3], a3);
    }
    pout[q * 256] = (a0 + a1) + (a2 + a3);
  }
}

// ---------------------------------------------------------------------------
// K5: reduce partials over 32 kchunks -> context
// ---------------------------------------------------------------------------
__global__ __launch_bounds__(256) void ctx_reduce(const float* __restrict__ part,
                                                  float* __restrict__ ctx) {
  const int o = blockIdx.x * 256 + threadIdx.x;  // [b][q][d]
  const int b = o >> 13, qd = o & 8191;
  const float* p = part + b * 32 * 8192 + qd;
  float a0 = 0.f, a1 = 0.f, a2 = 0.f, a3 = 0.f;
#pragma unroll
  for (int kc = 0; kc < 8; ++kc) {
    a0 += p[(kc * 4 + 0) * 8192];
    a1 += p[(kc * 4 + 1) * 8192];
    a2 += p[(kc * 4 + 2) * 8192];
    a3 += p[(kc * 4 + 3) * 8192];
  }
  ctx[o] = (a0 + a1) + (a2 + a3);
}

extern "C" void kernel_launch(void* const* d_in, const int* in_sizes, int n_in,
                              void* d_out, int out_size, void* d_ws, size_t ws_size,
                              hipStream_t stream) {
  const float* query = (const float*)d_in[0];  // [8][32][256]
  const float* keys  = (const float*)d_in[1];  // [8][2048][256]
  const float* Wq    = (const float*)d_in[2];  // [256][256]
  const float* Wk    = (const float*)d_in[3];  // [256][256]
  const float* v     = (const float*)d_in[4];  // [256]

  float* out  = (float*)d_out;
  float* ctx  = out;           // 65536 floats: context [8][32][256]
  float* attn = out + 65536;   // 524288 floats: attn [8][32][2048]

  float* ws   = (float*)d_ws;
  float* kp   = ws;            // 16384*256 = 4194304
  float* qp   = ws + 4194304;  // 256*256   = 65536
  float* sc   = ws + 4259840;  // 256*2048  = 524288
  float* part = ws + 4784128;  // 256*8192  = 2097152

  proj_gemm<<<dim3(130, 2), 256, 0, stream>>>(keys, Wk, kp, query, Wq, qp);
  score_kernel<<<dim3(32, 8), 1024, 0, stream>>>(kp, qp, v, sc);
  softmax_kernel<<<256, 256, 0, stream>>>(sc, attn);
  ctx_partial<<<dim3(32, 8), 256, 0, stream>>>(keys, attn, part);
  ctx_reduce<<<256, 256, 0, stream>>>(part, ctx);
}

// Round 3
// 86.004 us; speedup vs baseline: 1.4795x; 1.4795x over previous
//
#include <hip/hip_runtime.h>
#include <hip/hip_bf16.h>

#define SCALE_2LOG2E 2.8853900817779268f   // 2*log2(e): folded into projections
#define LOG2E 1.4426950408889634f

#define NB 8
#define TQ 32
#define TK 2048
#define DD 256

typedef __bf16 bf16x8 __attribute__((ext_vector_type(8)));
typedef float f32x4 __attribute__((ext_vector_type(4)));

// bf16 round-to-nearest-even split helpers (bit math: no header-type aliasing)
__device__ __forceinline__ unsigned short f2bf_u(float x) {
  unsigned int xi = __builtin_bit_cast(unsigned int, x);
  unsigned int r = (xi + 0x7fffu + ((xi >> 16) & 1u)) >> 16;
  return (unsigned short)r;
}
__device__ __forceinline__ float bf2f(unsigned short u) {
  return __builtin_bit_cast(float, (unsigned int)u << 16);
}

// ---------------------------------------------------------------------------
// K1: projection GEMM via bf16 hi/lo split MFMA.
// C[m][u] = SCALE * sum_d A[m][d] * W[u][d]   (both row-major, contraction on
// inner dim == the "B^T input" MFMA GEMM form).
// 64x64 tile, K=256 in 4 ksteps of 64. 256 thr = 4 waves, wave = 32x32 quadrant.
// a*w ~= ah*wh + ah*wl + al*wh  (lo*lo dropped, ~2^-18 relative).
// LDS: 4 planes [64 rows][64 k] bf16, XOR-swizzled (byte ^= (row&7)<<4) so the
// 16-lane row-slice ds_read_b128 covers all 32 banks.
// Grid: bx<1024 -> keys*Wk^T (256 mtiles x 4 ntiles); else query*Wq^T (4x4).
// ---------------------------------------------------------------------------
__global__ __launch_bounds__(256) void proj_mfma(const float* __restrict__ keys,
                                                 const float* __restrict__ Wk,
                                                 float* __restrict__ kpo,
                                                 const float* __restrict__ query,
                                                 const float* __restrict__ Wq,
                                                 float* __restrict__ qpo) {
  __shared__ unsigned short Ah[64 * 64], Al[64 * 64], Bh[64 * 64], Bl[64 * 64];
  const int tid = threadIdx.x;
  const int bx = blockIdx.x;
  const float* A; const float* W; float* C; int m0, n0;
  if (bx < 1024) {
    A = keys; W = Wk; C = kpo; m0 = (bx >> 2) * 64; n0 = (bx & 3) * 64;
  } else {
    int i = bx - 1024;
    A = query; W = Wq; C = qpo; m0 = (i >> 2) * 64; n0 = (i & 3) * 64;
  }
  const int lane = tid & 63;
  const int wv = tid >> 6;                    // 0..3
  const int wr = (wv >> 1) * 32, wc = (wv & 1) * 32;

  f32x4 acc[2][2] = {{{0.f, 0.f, 0.f, 0.f}, {0.f, 0.f, 0.f, 0.f}},
                     {{0.f, 0.f, 0.f, 0.f}, {0.f, 0.f, 0.f, 0.f}}};

  for (int k0 = 0; k0 < 256; k0 += 64) {
    if (k0) __syncthreads();
#pragma unroll
    for (int i = 0; i < 4; ++i) {
      int idx = tid + i * 256;                // 1024 float4s: 64 rows x 16
      int r = idx >> 4, c4 = idx & 15;
      float4 a = *(const float4*)(A + (m0 + r) * 256 + k0 + c4 * 4);
      float4 w = *(const float4*)(W + (n0 + r) * 256 + k0 + c4 * 4);
      int off = r * 128 + ((c4 * 8) ^ ((r & 7) << 4));   // byte offset
      ushort4 ah, al, wh, wl;
      ah.x = f2bf_u(a.x); al.x = f2bf_u(a.x - bf2f(ah.x));
      ah.y = f2bf_u(a.y); al.y = f2bf_u(a.y - bf2f(ah.y));
      ah.z = f2bf_u(a.z); al.z = f2bf_u(a.z - bf2f(ah.z));
      ah.w = f2bf_u(a.w); al.w = f2bf_u(a.w - bf2f(ah.w));
      wh.x = f2bf_u(w.x); wl.x = f2bf_u(w.x - bf2f(wh.x));
      wh.y = f2bf_u(w.y); wl.y = f2bf_u(w.y - bf2f(wh.y));
      wh.z = f2bf_u(w.z); wl.z = f2bf_u(w.z - bf2f(wh.z));
      wh.w = f2bf_u(w.w); wl.w = f2bf_u(w.w - bf2f(wh.w));
      *reinterpret_cast<ushort4*>(reinterpret_cast<char*>(Ah) + off) = ah;
      *reinterpret_cast<ushort4*>(reinterpret_cast<char*>(Al) + off) = al;
      *reinterpret_cast<ushort4*>(reinterpret_cast<char*>(Bh) + off) = wh;
      *reinterpret_cast<ushort4*>(reinterpret_cast<char*>(Bl) + off) = wl;
    }
    __syncthreads();
#pragma unroll
    for (int s = 0; s < 2; ++s) {             // ksub = s*32 within kstep
      bf16x8 a_h[2], a_l[2], b_h[2], b_l[2];
      const int kb = s * 64 + ((lane >> 4) << 4);   // byte offset of k in row
#pragma unroll
      for (int h = 0; h < 2; ++h) {
        int ra = wr + h * 16 + (lane & 15);
        int offa = ra * 128 + (kb ^ ((ra & 7) << 4));
        a_h[h] = *reinterpret_cast<const bf16x8*>(reinterpret_cast<const char*>(Ah) + offa);
        a_l[h] = *reinterpret_cast<const bf16x8*>(reinterpret_cast<const char*>(Al) + offa);
        int rb = wc + h * 16 + (lane & 15);
        int offb = rb * 128 + (kb ^ ((rb & 7) << 4));
        b_h[h] = *reinterpret_cast<const bf16x8*>(reinterpret_cast<const char*>(Bh) + offb);
        b_l[h] = *reinterpret_cast<const bf16x8*>(reinterpret_cast<const char*>(Bl) + offb);
      }
#pragma unroll
      for (int mh = 0; mh < 2; ++mh)
#pragma unroll
        for (int nh = 0; nh < 2; ++nh) {
          acc[mh][nh] = __builtin_amdgcn_mfma_f32_16x16x32_bf16(a_h[mh], b_h[nh], acc[mh][nh], 0, 0, 0);
          acc[mh][nh] = __builtin_amdgcn_mfma_f32_16x16x32_bf16(a_h[mh], b_l[nh], acc[mh][nh], 0, 0, 0);
          acc[mh][nh] = __builtin_amdgcn_mfma_f32_16x16x32_bf16(a_l[mh], b_h[nh], acc[mh][nh], 0, 0, 0);
        }
    }
  }
  // C/D layout (m89-verified): col = lane&15, row = (lane>>4)*4 + reg
#pragma unroll
  for (int mh = 0; mh < 2; ++mh)
#pragma unroll
    for (int nh = 0; nh < 2; ++nh)
#pragma unroll
      for (int j = 0; j < 4; ++j) {
        int row = m0 + wr + mh * 16 + (lane >> 4) * 4 + j;
        int col = n0 + wc + nh * 16 + (lane & 15);
        C[row * 256 + col] = acc[mh][nh][j] * SCALE_2LOG2E;
      }
}

// ---------------------------------------------------------------------------
// K2: scores[b][q][k] = V0 - 2*sum_u v[u]/(exp2(qp'+kp')+1)
// grid (32 kchunks, 8 b), 1024 threads (16 waves -> 4/SIMD). Wave w handles
// q rows {2w, 2w+1} interleaved: kp LDS read shared by both rows.
// ---------------------------------------------------------------------------
__global__ __launch_bounds__(1024) void score_kernel(const float* __restrict__ kproj,
                                                     const float* __restrict__ qproj,
                                                     const float* __restrict__ v,
                                                     float* __restrict__ scores) {
  __shared__ float kp[64 * 256];       // 64 KB
  const int tid = threadIdx.x;
  const int b = blockIdx.y;
  const int kbase = blockIdx.x * 64;
#pragma unroll
  for (int i = 0; i < 4; ++i) {
    int idx4 = tid + i * 1024;         // 0..4095 float4s
    int kk = idx4 >> 6, u4 = idx4 & 63;
    float4 t = *(const float4*)(kproj + (b * TK + kbase + kk) * 256 + u4 * 4);
    *(float4*)&kp[kk * 256 + ((u4 ^ (kk & 7)) << 2)] = t;
  }
  const int lane = tid & 63;
  float vs = (v[lane] + v[lane + 64]) + (v[lane + 128] + v[lane + 192]);
#pragma unroll
  for (int off = 32; off; off >>= 1) vs += __shfl_xor(vs, off, 64);
  __syncthreads();

  const int wv = tid >> 6;             // 0..15, q rows {2wv, 2wv+1}
  const int xorv = lane & 7;
  const float* qr0 = qproj + (b * TQ + wv * 2) * 256;
  const float* qr1 = qr0 + 256;
  float sc0 = 0.f, sc1 = 0.f;
#pragma unroll 4
  for (int u4 = 0; u4 < 64; ++u4) {
    float4 kpv = *(const float4*)&kp[lane * 256 + ((u4 ^ xorv) << 2)];
    float4 qa = *(const float4*)(qr0 + u4 * 4);   // uniform -> s_load
    float4 qb = *(const float4*)(qr1 + u4 * 4);   // uniform -> s_load
    float4 vv = *(const float4*)(v + u4 * 4);     // uniform -> s_load
    sc0 = fmaf(vv.x, __builtin_amdgcn_rcpf(__builtin_amdgcn_exp2f(kpv.x + qa.x) + 1.f), sc0);
    sc1 = fmaf(vv.x, __builtin_amdgcn_rcpf(__builtin_amdgcn_exp2f(kpv.x + qb.x) + 1.f), sc1);
    sc0 = fmaf(vv.y, __builtin_amdgcn_rcpf(__builtin_amdgcn_exp2f(kpv.y + qa.y) + 1.f), sc0);
    sc1 = fmaf(vv.y, __builtin_amdgcn_rcpf(__builtin_amdgcn_exp2f(kpv.y + qb.y) + 1.f), sc1);
    sc0 = fmaf(vv.z, __builtin_amdgcn_rcpf(__builtin_amdgcn_exp2f(kpv.z + qa.z) + 1.f), sc0);
    sc1 = fmaf(vv.z, __builtin_amdgcn_rcpf(__builtin_amdgcn_exp2f(kpv.z + qb.z) + 1.f), sc1);
    sc0 = fmaf(vv.w, __builtin_amdgcn_rcpf(__builtin_amdgcn_exp2f(kpv.w + qa.w) + 1.f), sc0);
    sc1 = fmaf(vv.w, __builtin_amdgcn_rcpf(__builtin_amdgcn_exp2f(kpv.w + qb.w) + 1.f), sc1);
  }
  float* srow = scores + (b * TQ + wv * 2) * TK + kbase + lane;
  srow[0]  = fmaf(-2.f, sc0, vs);
  srow[TK] = fmaf(-2.f, sc1, vs);
}

// ---------------------------------------------------------------------------
// K3: row softmax over 2048. One block per (b,q) row, 256 threads x 8 elems.
// ---------------------------------------------------------------------------
__global__ __launch_bounds__(256) void softmax_kernel(const float* __restrict__ scores,
                                                      float* __restrict__ attn) {
  const int row = blockIdx.x;
  const int tid = threadIdx.x;
  const float4* s4 = (const float4*)(scores + row * TK);
  float4 x0 = s4[tid], x1 = s4[tid + 256];
  float m = fmaxf(fmaxf(fmaxf(x0.x, x0.y), fmaxf(x0.z, x0.w)),
                  fmaxf(fmaxf(x1.x, x1.y), fmaxf(x1.z, x1.w)));
#pragma unroll
  for (int off = 32; off; off >>= 1) m = fmaxf(m, __shfl_xor(m, off, 64));
  __shared__ float redm[4], reds[4];
  const int lane = tid & 63, wv = tid >> 6;
  if (lane == 0) redm[wv] = m;
  __syncthreads();
  m = fmaxf(fmaxf(redm[0], redm[1]), fmaxf(redm[2], redm[3]));
  float e0 = __builtin_amdgcn_exp2f((x0.x - m) * LOG2E);
  float e1 = __builtin_amdgcn_exp2f((x0.y - m) * LOG2E);
  float e2 = __builtin_amdgcn_exp2f((x0.z - m) * LOG2E);
  float e3 = __builtin_amdgcn_exp2f((x0.w - m) * LOG2E);
  float e4 = __builtin_amdgcn_exp2f((x1.x - m) * LOG2E);
  float e5 = __builtin_amdgcn_exp2f((x1.y - m) * LOG2E);
  float e6 = __builtin_amdgcn_exp2f((x1.z - m) * LOG2E);
  float e7 = __builtin_amdgcn_exp2f((x1.w - m) * LOG2E);
  float s = ((e0 + e1) + (e2 + e3)) + ((e4 + e5) + (e6 + e7));
#pragma unroll
  for (int off = 32; off; off >>= 1) s += __shfl_xor(s, off, 64);
  if (lane == 0) reds[wv] = s;
  __syncthreads();
  float total = (reds[0] + reds[1]) + (reds[2] + reds[3]);
  float inv = __builtin_amdgcn_rcpf(total);
  float4* o4 = (float4*)(attn + row * TK);
  o4[tid] = make_float4(e0 * inv, e1 * inv, e2 * inv, e3 * inv);
  o4[tid + 256] = make_float4(e4 * inv, e5 * inv, e6 * inv, e7 * inv);
}

// ---------------------------------------------------------------------------
// K4: context partials: part[b][kc][q][d] = sum_{k in chunk} attn[b][q][k]*keys[b][k][d]
// ---------------------------------------------------------------------------
__global__ __launch_bounds__(256) void ctx_partial(const float* __restrict__ keys,
                                                   const float* __restrict__ attn,
                                                   float* __restrict__ part) {
  const int b = blockIdx.y, kc = blockIdx.x;
  const int d = threadIdx.x;
  const int kbase = kc * 64;
  float kv[64];
#pragma unroll
  for (int k = 0; k < 64; ++k)
    kv[k] = keys[(b * TK + kbase + k) * 256 + d];
  float* pout = part + (b * 32 + kc) * 8192 + d;
#pragma unroll 1
  for (int q = 0; q < 32; ++q) {
    const float4* ar = (const float4*)(attn + (b * TQ + q) * TK + kbase);  // uniform
    float a0 = 0.f, a1 = 0.f, a2 = 0.f, a3 = 0.f;
#pragma unroll
    for (int k4 = 0; k4 < 16; ++k4) {
      float4 av = ar[k4];
      a0 = fmaf(av.x, kv[k4 * 4 + 0], a0);
      a1 = fmaf(av.y, kv[k4 * 4 + 1], a1);
      a2 = fmaf(av.z, kv[k4 * 4 + 2], a2);
      a3 = fmaf(av.w, kv[k4 * 4 + 3], a3);
    }
    pout[q * 256] = (a0 + a1) + (a2 + a3);
  }
}

// ---------------------------------------------------------------------------
// K5: reduce partials over 32 kchunks -> context
// ---------------------------------------------------------------------------
__global__ __launch_bounds__(256) void ctx_reduce(const float* __restrict__ part,
                                                  float* __restrict__ ctx) {
  const int o = blockIdx.x * 256 + threadIdx.x;  // [b][q][d]
  const int b = o >> 13, qd = o & 8191;
  const float* p = part + b * 32 * 8192 + qd;
  float a0 = 0.f, a1 = 0.f, a2 = 0.f, a3 = 0.f;
#pragma unroll
  for (int kc = 0; kc < 8; ++kc) {
    a0 += p[(kc * 4 + 0) * 8192];
    a1 += p[(kc * 4 + 1) * 8192];
    a2 += p[(kc * 4 + 2) * 8192];
    a3 += p[(kc * 4 + 3) * 8192];
  }
  ctx[o] = (a0 + a1) + (a2 + a3);
}

extern "C" void kernel_launch(void* const* d_in, const int* in_sizes, int n_in,
                              void* d_out, int out_size, void* d_ws, size_t ws_size,
                              hipStream_t stream) {
  const float* query = (const float*)d_in[0];  // [8][32][256]
  const float* keys  = (const float*)d_in[1];  // [8][2048][256]
  const float* Wq    = (const float*)d_in[2];  // [256][256]
  const float* Wk    = (const float*)d_in[3];  // [256][256]
  const float* v     = (const float*)d_in[4];  // [256]

  float* out  = (float*)d_out;
  float* ctx  = out;           // 65536 floats: context [8][32][256]
  float* attn = out + 65536;   // 524288 floats: attn [8][32][2048]

  float* ws   = (float*)d_ws;
  float* kp   = ws;            // 16384*256 = 4194304
  float* qp   = ws + 4194304;  // 256*256   = 65536
  float* sc   = ws + 4259840;  // 256*2048  = 524288
  float* part = ws + 4784128;  // 256*8192  = 2097152

  proj_mfma<<<dim3(1040), 256, 0, stream>>>(keys, Wk, kp, query, Wq, qp);
  score_kernel<<<dim3(32, 8), 1024, 0, stream>>>(kp, qp, v, sc);
  softmax_kernel<<<256, 256, 0, stream>>>(sc, attn);
  ctx_partial<<<dim3(32, 8), 256, 0, stream>>>(keys, attn, part);
  ctx_reduce<<<256, 256, 0, stream>>>(part, ctx);
}

// Round 4
// 79.850 us; speedup vs baseline: 1.5936x; 1.0771x over previous
//
#include <hip/hip_runtime.h>
#include <hip/hip_bf16.h>

#define SCALE_2LOG2E 2.8853900817779268f   // 2*log2(e): folded into projections
#define LOG2E 1.4426950408889634f

#define NB 8
#define TQ 32
#define TK 2048
#define DD 256

typedef unsigned short u16;
typedef u16 u16x8 __attribute__((ext_vector_type(8)));
typedef __bf16 bf16x8 __attribute__((ext_vector_type(8)));
typedef float f32x4 __attribute__((ext_vector_type(4)));

// bf16 round-to-nearest-even split helpers (bit math: no header-type aliasing)
__device__ __forceinline__ u16 f2bf_u(float x) {
  unsigned int xi = __builtin_bit_cast(unsigned int, x);
  unsigned int r = (xi + 0x7fffu + ((xi >> 16) & 1u)) >> 16;
  return (u16)r;
}
__device__ __forceinline__ float bf2f(u16 u) {
  return __builtin_bit_cast(float, (unsigned int)u << 16);
}

// ---------------------------------------------------------------------------
// K0: one-shot fp32 -> bf16 hi/lo plane conversion (linear row-major layout).
// Regions: keys (2048 blocks), query (32), Wk (32), Wq (32). 8 elems/thread.
// ---------------------------------------------------------------------------
__global__ __launch_bounds__(256) void convert_kernel(
    const float* __restrict__ keys, const float* __restrict__ query,
    const float* __restrict__ Wk, const float* __restrict__ Wq,
    u16* __restrict__ kh, u16* __restrict__ kl, u16* __restrict__ qh, u16* __restrict__ ql,
    u16* __restrict__ wkh, u16* __restrict__ wkl, u16* __restrict__ wqh, u16* __restrict__ wql) {
  const int bx = blockIdx.x;
  const float* src; u16 *dh, *dl; int base;
  if (bx < 2048)      { src = keys;  dh = kh;  dl = kl;  base = 0; }
  else if (bx < 2080) { src = query; dh = qh;  dl = ql;  base = 2048; }
  else if (bx < 2112) { src = Wk;    dh = wkh; dl = wkl; base = 2080; }
  else                { src = Wq;    dh = wqh; dl = wql; base = 2112; }
  const int chunk = (bx - base) * 256 + threadIdx.x;   // 8-element chunk
  const float4* s4 = (const float4*)(src + chunk * 8);
  float4 x0 = s4[0], x1 = s4[1];
  const float xs[8] = {x0.x, x0.y, x0.z, x0.w, x1.x, x1.y, x1.z, x1.w};
  u16x8 h, l;
#pragma unroll
  for (int i = 0; i < 8; ++i) {
    u16 hh = f2bf_u(xs[i]);
    h[i] = hh;
    l[i] = f2bf_u(xs[i] - bf2f(hh));
  }
  *(u16x8*)(dh + chunk * 8) = h;
  *(u16x8*)(dl + chunk * 8) = l;
}

// ---------------------------------------------------------------------------
// K1: projection GEMM via bf16 hi/lo split MFMA, pre-converted operands.
// C[m][u] = SCALE * sum_d A[m][d]*W[u][d].  64x64 tile, 4 waves (32x32 each),
// BK=64 (4 ksteps). LDS: 4 planes [64][64] u16 (8KB each, 32KB total),
// XOR-swizzled in 16B chunks: chunk' = chunk ^ (row&7) -> structural-minimum
// bank phases on both ds_write_b128 (staging) and ds_read_b128 (fragments).
// Wave w stages plane w (8 global b128 -> 8 ds_write per kstep).
// ---------------------------------------------------------------------------
__global__ __launch_bounds__(256) void proj_mfma(
    const u16* __restrict__ kh, const u16* __restrict__ kl,
    const u16* __restrict__ wkh, const u16* __restrict__ wkl, float* __restrict__ kpo,
    const u16* __restrict__ qh, const u16* __restrict__ ql,
    const u16* __restrict__ wqh, const u16* __restrict__ wql, float* __restrict__ qpo) {
  __shared__ u16 S[4 * 4096];          // [plane][64 rows][64 k]
  const int tid = threadIdx.x, lane = tid & 63, wv = tid >> 6;
  const int bx = blockIdx.x;
  const u16 *ah, *al, *bh, *bl; float* C; int m0, n0;
  if (bx < 1024) {
    ah = kh; al = kl; bh = wkh; bl = wkl; C = kpo;
    m0 = (bx >> 2) * 64; n0 = (bx & 3) * 64;
  } else {
    int i = bx - 1024;
    ah = qh; al = ql; bh = wqh; bl = wql; C = qpo;
    m0 = (i >> 2) * 64; n0 = (i & 3) * 64;
  }
  const int wr = (wv >> 1) * 32, wc = (wv & 1) * 32;

  const u16* mysrc; int rbase;
  if (wv == 0)      { mysrc = ah; rbase = m0; }
  else if (wv == 1) { mysrc = al; rbase = m0; }
  else if (wv == 2) { mysrc = bh; rbase = n0; }
  else              { mysrc = bl; rbase = n0; }
  u16* myp = &S[wv * 4096];
  const int srow = lane >> 3, scol = lane & 7;       // staging row-in-8 / chunk
  const u16* gbase = mysrc + (rbase + srow) * 256 + scol * 8;
  const int ldsw = srow * 64 + ((scol ^ srow) << 3); // row&7 == srow for j*8+srow

  f32x4 acc[2][2] = {{{0.f, 0.f, 0.f, 0.f}, {0.f, 0.f, 0.f, 0.f}},
                     {{0.f, 0.f, 0.f, 0.f}, {0.f, 0.f, 0.f, 0.f}}};

  for (int ks = 0; ks < 4; ++ks) {
    const int k0 = ks * 64;
    u16x8 st[8];
#pragma unroll
    for (int j = 0; j < 8; ++j)
      st[j] = *(const u16x8*)(gbase + k0 + j * 2048);  // 8 rows apart
    if (ks) __syncthreads();                           // prev reads done
#pragma unroll
    for (int j = 0; j < 8; ++j)
      *(u16x8*)&myp[j * 512 + ldsw] = st[j];
    __syncthreads();                                   // writes visible
#pragma unroll
    for (int s = 0; s < 2; ++s) {                      // ksub: k = s*32..s*32+31
      bf16x8 fa[2][2], fb[2][2];                       // [half][hi/lo]
#pragma unroll
      for (int h = 0; h < 2; ++h) {
        int ra = wr + h * 16 + (lane & 15);
        int offa = ra * 64 + (((s * 4 + (lane >> 4)) ^ (ra & 7)) << 3);
        fa[h][0] = __builtin_bit_cast(bf16x8, *(const u16x8*)&S[offa]);
        fa[h][1] = __builtin_bit_cast(bf16x8, *(const u16x8*)&S[4096 + offa]);
        int rb = wc + h * 16 + (lane & 15);
        int offb = rb * 64 + (((s * 4 + (lane >> 4)) ^ (rb & 7)) << 3);
        fb[h][0] = __builtin_bit_cast(bf16x8, *(const u16x8*)&S[8192 + offb]);
        fb[h][1] = __builtin_bit_cast(bf16x8, *(const u16x8*)&S[12288 + offb]);
      }
#pragma unroll
      for (int mh = 0; mh < 2; ++mh)
#pragma unroll
        for (int nh = 0; nh < 2; ++nh) {
          acc[mh][nh] = __builtin_amdgcn_mfma_f32_16x16x32_bf16(fa[mh][0], fb[nh][0], acc[mh][nh], 0, 0, 0);
          acc[mh][nh] = __builtin_amdgcn_mfma_f32_16x16x32_bf16(fa[mh][0], fb[nh][1], acc[mh][nh], 0, 0, 0);
          acc[mh][nh] = __builtin_amdgcn_mfma_f32_16x16x32_bf16(fa[mh][1], fb[nh][0], acc[mh][nh], 0, 0, 0);
        }
    }
  }
  // C/D layout (m89-verified): col = lane&15, row = (lane>>4)*4 + reg
#pragma unroll
  for (int mh = 0; mh < 2; ++mh)
#pragma unroll
    for (int nh = 0; nh < 2; ++nh)
#pragma unroll
      for (int j = 0; j < 4; ++j) {
        int row = m0 + wr + mh * 16 + (lane >> 4) * 4 + j;
        int col = n0 + wc + nh * 16 + (lane & 15);
        C[row * 256 + col] = acc[mh][nh][j] * SCALE_2LOG2E;
      }
}

// ---------------------------------------------------------------------------
// K2: scores[b][q][k] = V0 - 2*sum_u v[u]/(exp2(qp'+kp')+1)
// grid (32 kchunks, 8 b), 1024 threads (16 waves). Wave w: q rows {2w,2w+1}.
// ---------------------------------------------------------------------------
__global__ __launch_bounds__(1024) void score_kernel(const float* __restrict__ kproj,
                                                     const float* __restrict__ qproj,
                                                     const float* __restrict__ v,
                                                     float* __restrict__ scores) {
  __shared__ float kp[64 * 256];       // 64 KB
  const int tid = threadIdx.x;
  const int b = blockIdx.y;
  const int kbase = blockIdx.x * 64;
#pragma unroll
  for (int i = 0; i < 4; ++i) {
    int idx4 = tid + i * 1024;         // 0..4095 float4s
    int kk = idx4 >> 6, u4 = idx4 & 63;
    float4 t = *(const float4*)(kproj + (b * TK + kbase + kk) * 256 + u4 * 4);
    *(float4*)&kp[kk * 256 + ((u4 ^ (kk & 7)) << 2)] = t;
  }
  const int lane = tid & 63;
  float vs = (v[lane] + v[lane + 64]) + (v[lane + 128] + v[lane + 192]);
#pragma unroll
  for (int off = 32; off; off >>= 1) vs += __shfl_xor(vs, off, 64);
  __syncthreads();

  const int wv = tid >> 6;             // 0..15, q rows {2wv, 2wv+1}
  const int xorv = lane & 7;
  const float* qr0 = qproj + (b * TQ + wv * 2) * 256;
  const float* qr1 = qr0 + 256;
  float sc0 = 0.f, sc1 = 0.f;
#pragma unroll 4
  for (int u4 = 0; u4 < 64; ++u4) {
    float4 kpv = *(const float4*)&kp[lane * 256 + ((u4 ^ xorv) << 2)];
    float4 qa = *(const float4*)(qr0 + u4 * 4);   // uniform -> s_load
    float4 qb = *(const float4*)(qr1 + u4 * 4);   // uniform -> s_load
    float4 vv = *(const float4*)(v + u4 * 4);     // uniform -> s_load
    sc0 = fmaf(vv.x, __builtin_amdgcn_rcpf(__builtin_amdgcn_exp2f(kpv.x + qa.x) + 1.f), sc0);
    sc1 = fmaf(vv.x, __builtin_amdgcn_rcpf(__builtin_amdgcn_exp2f(kpv.x + qb.x) + 1.f), sc1);
    sc0 = fmaf(vv.y, __builtin_amdgcn_rcpf(__builtin_amdgcn_exp2f(kpv.y + qa.y) + 1.f), sc0);
    sc1 = fmaf(vv.y, __builtin_amdgcn_rcpf(__builtin_amdgcn_exp2f(kpv.y + qb.y) + 1.f), sc1);
    sc0 = fmaf(vv.z, __builtin_amdgcn_rcpf(__builtin_amdgcn_exp2f(kpv.z + qa.z) + 1.f), sc0);
    sc1 = fmaf(vv.z, __builtin_amdgcn_rcpf(__builtin_amdgcn_exp2f(kpv.z + qb.z) + 1.f), sc1);
    sc0 = fmaf(vv.w, __builtin_amdgcn_rcpf(__builtin_amdgcn_exp2f(kpv.w + qa.w) + 1.f), sc0);
    sc1 = fmaf(vv.w, __builtin_amdgcn_rcpf(__builtin_amdgcn_exp2f(kpv.w + qb.w) + 1.f), sc1);
  }
  float* srow = scores + (b * TQ + wv * 2) * TK + kbase + lane;
  srow[0]  = fmaf(-2.f, sc0, vs);
  srow[TK] = fmaf(-2.f, sc1, vs);
}

// ---------------------------------------------------------------------------
// K3: row softmax over 2048. One block per (b,q) row, 256 threads x 8 elems.
// ---------------------------------------------------------------------------
__global__ __launch_bounds__(256) void softmax_kernel(const float* __restrict__ scores,
                                                      float* __restrict__ attn) {
  const int row = blockIdx.x;
  const int tid = threadIdx.x;
  const float4* s4 = (const float4*)(scores + row * TK);
  float4 x0 = s4[tid], x1 = s4[tid + 256];
  float m = fmaxf(fmaxf(fmaxf(x0.x, x0.y), fmaxf(x0.z, x0.w)),
                  fmaxf(fmaxf(x1.x, x1.y), fmaxf(x1.z, x1.w)));
#pragma unroll
  for (int off = 32; off; off >>= 1) m = fmaxf(m, __shfl_xor(m, off, 64));
  __shared__ float redm[4], reds[4];
  const int lane = tid & 63, wv = tid >> 6;
  if (lane == 0) redm[wv] = m;
  __syncthreads();
  m = fmaxf(fmaxf(redm[0], redm[1]), fmaxf(redm[2], redm[3]));
  float e0 = __builtin_amdgcn_exp2f((x0.x - m) * LOG2E);
  float e1 = __builtin_amdgcn_exp2f((x0.y - m) * LOG2E);
  float e2 = __builtin_amdgcn_exp2f((x0.z - m) * LOG2E);
  float e3 = __builtin_amdgcn_exp2f((x0.w - m) * LOG2E);
  float e4 = __builtin_amdgcn_exp2f((x1.x - m) * LOG2E);
  float e5 = __builtin_amdgcn_exp2f((x1.y - m) * LOG2E);
  float e6 = __builtin_amdgcn_exp2f((x1.z - m) * LOG2E);
  float e7 = __builtin_amdgcn_exp2f((x1.w - m) * LOG2E);
  float s = ((e0 + e1) + (e2 + e3)) + ((e4 + e5) + (e6 + e7));
#pragma unroll
  for (int off = 32; off; off >>= 1) s += __shfl_xor(s, off, 64);
  if (lane == 0) reds[wv] = s;
  __syncthreads();
  float total = (reds[0] + reds[1]) + (reds[2] + reds[3]);
  float inv = __builtin_amdgcn_rcpf(total);
  float4* o4 = (float4*)(attn + row * TK);
  o4[tid] = make_float4(e0 * inv, e1 * inv, e2 * inv, e3 * inv);
  o4[tid + 256] = make_float4(e4 * inv, e5 * inv, e6 * inv, e7 * inv);
}

// ---------------------------------------------------------------------------
// K4: context partials. grid (32 kc, 8 b, 2 qhalf): 512 blocks, 2/CU.
// part[b][kc][q][d] = sum_{k in chunk} attn[b][q][k]*keys[b][k][d]
// ---------------------------------------------------------------------------
__global__ __launch_bounds__(256) void ctx_partial(const float* __restrict__ keys,
                                                   const float* __restrict__ attn,
                                                   float* __restrict__ part) {
  const int b = blockIdx.y, kc = blockIdx.x, q0 = blockIdx.z * 16;
  const int d = threadIdx.x;
  const int kbase = kc * 64;
  float kv[64];
#pragma unroll
  for (int k = 0; k < 64; ++k)
    kv[k] = keys[(b * TK + kbase + k) * 256 + d];
  float* pout = part + (b * 32 + kc) * 8192 + q0 * 256 + d;
#pragma unroll 1
  for (int q = 0; q < 16; ++q) {
    const float4* ar = (const float4*)(attn + (b * TQ + q0 + q) * TK + kbase);  // uniform
    float a0 = 0.f, a1 = 0.f, a2 = 0.f, a3 = 0.f;
#pragma unroll
    for (int k4 = 0; k4 < 16; ++k4) {
      float4 av = ar[k4];
      a0 = fmaf(av.x, kv[k4 * 4 + 0], a0);
      a1 = fmaf(av.y, kv[k4 * 4 + 1], a1);
      a2 = fmaf(av.z, kv[k4 * 4 + 2], a2);
      a3 = fmaf(av.w, kv[k4 * 4 + 3], a3);
    }
    pout[q * 256] = (a0 + a1) + (a2 + a3);
  }
}

// ---------------------------------------------------------------------------
// K5: reduce partials over 32 kchunks -> context
// ---------------------------------------------------------------------------
__global__ __launch_bounds__(256) void ctx_reduce(const float* __restrict__ part,
                                                  float* __restrict__ ctx) {
  const int o = blockIdx.x * 256 + threadIdx.x;  // [b][q][d]
  const int b = o >> 13, qd = o & 8191;
  const float* p = part + b * 32 * 8192 + qd;
  float a0 = 0.f, a1 = 0.f, a2 = 0.f, a3 = 0.f;
#pragma unroll
  for (int kc = 0; kc < 8; ++kc) {
    a0 += p[(kc * 4 + 0) * 8192];
    a1 += p[(kc * 4 + 1) * 8192];
    a2 += p[(kc * 4 + 2) * 8192];
    a3 += p[(kc * 4 + 3) * 8192];
  }
  ctx[o] = (a0 + a1) + (a2 + a3);
}

extern "C" void kernel_launch(void* const* d_in, const int* in_sizes, int n_in,
                              void* d_out, int out_size, void* d_ws, size_t ws_size,
                              hipStream_t stream) {
  const float* query = (const float*)d_in[0];  // [8][32][256]
  const float* keys  = (const float*)d_in[1];  // [8][2048][256]
  const float* Wq    = (const float*)d_in[2];  // [256][256]
  const float* Wk    = (const float*)d_in[3];  // [256][256]
  const float* v     = (const float*)d_in[4];  // [256]

  float* out  = (float*)d_out;
  float* ctx  = out;           // 65536 floats: context [8][32][256]
  float* attn = out + 65536;   // 524288 floats: attn [8][32][2048]

  float* ws   = (float*)d_ws;
  float* kp   = ws;                  // 4194304 f
  float* qp   = ws + 4194304;        // 65536 f
  float* sc   = ws + 4259840;        // 524288 f
  float* part = ws + 4784128;        // 2097152 f
  u16* u   = (u16*)(ws + 6881280);
  u16* kh  = u;                      // 4194304 u16
  u16* kl  = kh + 4194304;
  u16* qh  = kl + 4194304;           // 65536
  u16* ql  = qh + 65536;
  u16* wkh = ql + 65536;
  u16* wkl = wkh + 65536;
  u16* wqh = wkl + 65536;
  u16* wql = wqh + 65536;

  convert_kernel<<<2144, 256, 0, stream>>>(keys, query, Wk, Wq,
                                           kh, kl, qh, ql, wkh, wkl, wqh, wql);
  proj_mfma<<<1040, 256, 0, stream>>>(kh, kl, wkh, wkl, kp, qh, ql, wqh, wql, qp);
  score_kernel<<<dim3(32, 8), 1024, 0, stream>>>(kp, qp, v, sc);
  softmax_kernel<<<256, 256, 0, stream>>>(sc, attn);
  ctx_partial<<<dim3(32, 8, 2), 256, 0, stream>>>(keys, attn, part);
  ctx_reduce<<<256, 256, 0, stream>>>(part, ctx);
}

// Round 5
// 75.966 us; speedup vs baseline: 1.6750x; 1.0511x over previous
//
#include <hip/hip_runtime.h>
#include <hip/hip_bf16.h>

#define SCALE_2LOG2E 2.8853900817779268f   // 2*log2(e): folded into projections
#define LOG2E 1.4426950408889634f

#define NB 8
#define TQ 32
#define TK 2048
#define DD 256

typedef unsigned short u16;
typedef u16 u16x8 __attribute__((ext_vector_type(8)));
typedef __bf16 bf16x8 __attribute__((ext_vector_type(8)));
typedef float f32x4 __attribute__((ext_vector_type(4)));

// bf16 round-to-nearest-even split helpers (bit math: no header-type aliasing)
__device__ __forceinline__ u16 f2bf_u(float x) {
  unsigned int xi = __builtin_bit_cast(unsigned int, x);
  unsigned int r = (xi + 0x7fffu + ((xi >> 16) & 1u)) >> 16;
  return (u16)r;
}
__device__ __forceinline__ float bf2f(u16 u) {
  return __builtin_bit_cast(float, (unsigned int)u << 16);
}

// ---------------------------------------------------------------------------
// K0: fp32 -> bf16 hi/lo planes for Wk, Wq only (keys/query convert is fused
// into proj staging). 64 blocks x 256 thr x 8 elems.
// ---------------------------------------------------------------------------
__global__ __launch_bounds__(256) void convert_kernel(
    const float* __restrict__ Wk, const float* __restrict__ Wq,
    u16* __restrict__ wkh, u16* __restrict__ wkl,
    u16* __restrict__ wqh, u16* __restrict__ wql) {
  const int bx = blockIdx.x;
  const float* src; u16 *dh, *dl; int base;
  if (bx < 32) { src = Wk; dh = wkh; dl = wkl; base = 0; }
  else         { src = Wq; dh = wqh; dl = wql; base = 32; }
  const int chunk = (bx - base) * 256 + threadIdx.x;   // 8-element chunk
  const float4* s4 = (const float4*)(src + chunk * 8);
  float4 x0 = s4[0], x1 = s4[1];
  const float xs[8] = {x0.x, x0.y, x0.z, x0.w, x1.x, x1.y, x1.z, x1.w};
  u16x8 h, l;
#pragma unroll
  for (int i = 0; i < 8; ++i) {
    u16 hh = f2bf_u(xs[i]);
    h[i] = hh;
    l[i] = f2bf_u(xs[i] - bf2f(hh));
  }
  *(u16x8*)(dh + chunk * 8) = h;
  *(u16x8*)(dl + chunk * 8) = l;
}

// ---------------------------------------------------------------------------
// K1: fused convert+GEMM. C[m][u] = SCALE * sum_d A[m][d] * W[u][d].
// Tile 64(m) x 256(full n): each A (keys/query) element read & converted
// exactly ONCE across the whole grid. 512 thr = 8 waves, wave = 32x64 output
// (2 m-frags x 4 n-frags). BK=64, 4 ksteps.
// LDS 80KB: Ah/Al [64][64] u16 + Bh/Bl [256][64] u16. Row = 128B; 16B-chunk
// XOR swizzle (c ^= row&7) -> fragment ds_read_b128 covers all 32 banks.
// A is converted in-register during staging; B planes come pre-converted
// (256KB, L2-resident).
// Grid: bx<256 -> keys tile bx; bx>=256 -> query tile bx-256.
// ---------------------------------------------------------------------------
__global__ __launch_bounds__(512) void proj_fused(
    const float* __restrict__ keys, const float* __restrict__ query,
    const u16* __restrict__ wkh, const u16* __restrict__ wkl,
    const u16* __restrict__ wqh, const u16* __restrict__ wql,
    float* __restrict__ kpo, float* __restrict__ qpo) {
  __shared__ u16 Ah[64 * 64], Al[64 * 64];
  __shared__ u16 Bh[256 * 64], Bl[256 * 64];
  const int tid = threadIdx.x, lane = tid & 63, wv = tid >> 6;
  const int bx = blockIdx.x;
  const float* A; const u16 *bhg, *blg; float* C; int m0;
  if (bx < 256) { A = keys;  bhg = wkh; blg = wkl; C = kpo; m0 = bx * 64; }
  else          { A = query; bhg = wqh; blg = wql; C = qpo; m0 = (bx - 256) * 64; }
  const int wr = (wv >> 2) * 32, wc = (wv & 3) * 64;

  // staging coords
  const int arow = tid >> 3, ac = tid & 7;             // A: row 0..63, chunk 0..7
  const float* ag = A + (m0 + arow) * 256 + ac * 8;
  const int aoff = arow * 64 + ((ac ^ (arow & 7)) << 3);

  f32x4 acc[2][4];
#pragma unroll
  for (int i = 0; i < 2; ++i)
#pragma unroll
    for (int j = 0; j < 4; ++j) acc[i][j] = {0.f, 0.f, 0.f, 0.f};

  for (int ks = 0; ks < 4; ++ks) {
    const int k0 = ks * 64;
    // issue global loads
    float4 a0 = *(const float4*)(ag + k0);
    float4 a1 = *(const float4*)(ag + k0 + 4);
    u16x8 sbh[4], sbl[4];
    int boff[4];
#pragma unroll
    for (int j = 0; j < 4; ++j) {
      int idx = tid + j * 512;                          // 0..2047
      int row = idx >> 3, c = idx & 7;
      sbh[j] = *(const u16x8*)(bhg + row * 256 + k0 + c * 8);
      sbl[j] = *(const u16x8*)(blg + row * 256 + k0 + c * 8);
      boff[j] = row * 64 + ((c ^ (row & 7)) << 3);
    }
    // convert A in-register
    const float as[8] = {a0.x, a0.y, a0.z, a0.w, a1.x, a1.y, a1.z, a1.w};
    u16x8 hA, lA;
#pragma unroll
    for (int i = 0; i < 8; ++i) {
      u16 hh = f2bf_u(as[i]);
      hA[i] = hh;
      lA[i] = f2bf_u(as[i] - bf2f(hh));
    }
    if (ks) __syncthreads();                            // prev-step reads done
    *(u16x8*)&Ah[aoff] = hA;
    *(u16x8*)&Al[aoff] = lA;
#pragma unroll
    for (int j = 0; j < 4; ++j) {
      *(u16x8*)&Bh[boff[j]] = sbh[j];
      *(u16x8*)&Bl[boff[j]] = sbl[j];
    }
    __syncthreads();                                    // writes visible
#pragma unroll
    for (int s = 0; s < 2; ++s) {                       // ksub: 32 k each
      const int kc = s * 4 + (lane >> 4);               // 16B chunk in row
      bf16x8 fa[2][2], fb[4][2];                        // [frag][hi/lo]
#pragma unroll
      for (int mh = 0; mh < 2; ++mh) {
        int ra = wr + mh * 16 + (lane & 15);
        int off = ra * 64 + ((kc ^ (ra & 7)) << 3);
        fa[mh][0] = __builtin_bit_cast(bf16x8, *(const u16x8*)&Ah[off]);
        fa[mh][1] = __builtin_bit_cast(bf16x8, *(const u16x8*)&Al[off]);
      }
#pragma unroll
      for (int nh = 0; nh < 4; ++nh) {
        int rb = wc + nh * 16 + (lane & 15);
        int off = rb * 64 + ((kc ^ (rb & 7)) << 3);
        fb[nh][0] = __builtin_bit_cast(bf16x8, *(const u16x8*)&Bh[off]);
        fb[nh][1] = __builtin_bit_cast(bf16x8, *(const u16x8*)&Bl[off]);
      }
#pragma unroll
      for (int mh = 0; mh < 2; ++mh)
#pragma unroll
        for (int nh = 0; nh < 4; ++nh) {
          acc[mh][nh] = __builtin_amdgcn_mfma_f32_16x16x32_bf16(fa[mh][0], fb[nh][0], acc[mh][nh], 0, 0, 0);
          acc[mh][nh] = __builtin_amdgcn_mfma_f32_16x16x32_bf16(fa[mh][0], fb[nh][1], acc[mh][nh], 0, 0, 0);
          acc[mh][nh] = __builtin_amdgcn_mfma_f32_16x16x32_bf16(fa[mh][1], fb[nh][0], acc[mh][nh], 0, 0, 0);
        }
    }
  }
  // C/D layout (m89-verified): col = lane&15, row = (lane>>4)*4 + reg
#pragma unroll
  for (int mh = 0; mh < 2; ++mh)
#pragma unroll
    for (int nh = 0; nh < 4; ++nh)
#pragma unroll
      for (int j = 0; j < 4; ++j) {
        int row = m0 + wr + mh * 16 + (lane >> 4) * 4 + j;
        int col = wc + nh * 16 + (lane & 15);
        C[row * 256 + col] = acc[mh][nh][j] * SCALE_2LOG2E;
      }
}

// ---------------------------------------------------------------------------
// K2: scores[b][q][k] = V0 - 2*sum_u v[u]/(exp2(qp'+kp')+1)
// grid (32 kchunks, 8 b), 1024 threads (16 waves). Wave w: q rows {2w,2w+1}.
// ---------------------------------------------------------------------------
__global__ __launch_bounds__(1024) void score_kernel(const float* __restrict__ kproj,
                                                     const float* __restrict__ qproj,
                                                     const float* __restrict__ v,
                                                     float* __restrict__ scores) {
  __shared__ float kp[64 * 256];       // 64 KB
  const int tid = threadIdx.x;
  const int b = blockIdx.y;
  const int kbase = blockIdx.x * 64;
#pragma unroll
  for (int i = 0; i < 4; ++i) {
    int idx4 = tid + i * 1024;         // 0..4095 float4s
    int kk = idx4 >> 6, u4 = idx4 & 63;
    float4 t = *(const float4*)(kproj + (b * TK + kbase + kk) * 256 + u4 * 4);
    *(float4*)&kp[kk * 256 + ((u4 ^ (kk & 7)) << 2)] = t;
  }
  const int lane = tid & 63;
  float vs = (v[lane] + v[lane + 64]) + (v[lane + 128] + v[lane + 192]);
#pragma unroll
  for (int off = 32; off; off >>= 1) vs += __shfl_xor(vs, off, 64);
  __syncthreads();

  const int wv = tid >> 6;             // 0..15, q rows {2wv, 2wv+1}
  const int xorv = lane & 7;
  const float* qr0 = qproj + (b * TQ + wv * 2) * 256;
  const float* qr1 = qr0 + 256;
  float sc0 = 0.f, sc1 = 0.f;
#pragma unroll 4
  for (int u4 = 0; u4 < 64; ++u4) {
    float4 kpv = *(const float4*)&kp[lane * 256 + ((u4 ^ xorv) << 2)];
    float4 qa = *(const float4*)(qr0 + u4 * 4);   // uniform -> s_load
    float4 qb = *(const float4*)(qr1 + u4 * 4);   // uniform -> s_load
    float4 vv = *(const float4*)(v + u4 * 4);     // uniform -> s_load
    sc0 = fmaf(vv.x, __builtin_amdgcn_rcpf(__builtin_amdgcn_exp2f(kpv.x + qa.x) + 1.f), sc0);
    sc1 = fmaf(vv.x, __builtin_amdgcn_rcpf(__builtin_amdgcn_exp2f(kpv.x + qb.x) + 1.f), sc1);
    sc0 = fmaf(vv.y, __builtin_amdgcn_rcpf(__builtin_amdgcn_exp2f(kpv.y + qa.y) + 1.f), sc0);
    sc1 = fmaf(vv.y, __builtin_amdgcn_rcpf(__builtin_amdgcn_exp2f(kpv.y + qb.y) + 1.f), sc1);
    sc0 = fmaf(vv.z, __builtin_amdgcn_rcpf(__builtin_amdgcn_exp2f(kpv.z + qa.z) + 1.f), sc0);
    sc1 = fmaf(vv.z, __builtin_amdgcn_rcpf(__builtin_amdgcn_exp2f(kpv.z + qb.z) + 1.f), sc1);
    sc0 = fmaf(vv.w, __builtin_amdgcn_rcpf(__builtin_amdgcn_exp2f(kpv.w + qa.w) + 1.f), sc0);
    sc1 = fmaf(vv.w, __builtin_amdgcn_rcpf(__builtin_amdgcn_exp2f(kpv.w + qb.w) + 1.f), sc1);
  }
  float* srow = scores + (b * TQ + wv * 2) * TK + kbase + lane;
  srow[0]  = fmaf(-2.f, sc0, vs);
  srow[TK] = fmaf(-2.f, sc1, vs);
}

// ---------------------------------------------------------------------------
// K3: row softmax over 2048. One block per (b,q) row, 256 threads x 8 elems.
// ---------------------------------------------------------------------------
__global__ __launch_bounds__(256) void softmax_kernel(const float* __restrict__ scores,
                                                      float* __restrict__ attn) {
  const int row = blockIdx.x;
  const int tid = threadIdx.x;
  const float4* s4 = (const float4*)(scores + row * TK);
  float4 x0 = s4[tid], x1 = s4[tid + 256];
  float m = fmaxf(fmaxf(fmaxf(x0.x, x0.y), fmaxf(x0.z, x0.w)),
                  fmaxf(fmaxf(x1.x, x1.y), fmaxf(x1.z, x1.w)));
#pragma unroll
  for (int off = 32; off; off >>= 1) m = fmaxf(m, __shfl_xor(m, off, 64));
  __shared__ float redm[4], reds[4];
  const int lane = tid & 63, wv = tid >> 6;
  if (lane == 0) redm[wv] = m;
  __syncthreads();
  m = fmaxf(fmaxf(redm[0], redm[1]), fmaxf(redm[2], redm[3]));
  float e0 = __builtin_amdgcn_exp2f((x0.x - m) * LOG2E);
  float e1 = __builtin_amdgcn_exp2f((x0.y - m) * LOG2E);
  float e2 = __builtin_amdgcn_exp2f((x0.z - m) * LOG2E);
  float e3 = __builtin_amdgcn_exp2f((x0.w - m) * LOG2E);
  float e4 = __builtin_amdgcn_exp2f((x1.x - m) * LOG2E);
  float e5 = __builtin_amdgcn_exp2f((x1.y - m) * LOG2E);
  float e6 = __builtin_amdgcn_exp2f((x1.z - m) * LOG2E);
  float e7 = __builtin_amdgcn_exp2f((x1.w - m) * LOG2E);
  float s = ((e0 + e1) + (e2 + e3)) + ((e4 + e5) + (e6 + e7));
#pragma unroll
  for (int off = 32; off; off >>= 1) s += __shfl_xor(s, off, 64);
  if (lane == 0) reds[wv] = s;
  __syncthreads();
  float total = (reds[0] + reds[1]) + (reds[2] + reds[3]);
  float inv = __builtin_amdgcn_rcpf(total);
  float4* o4 = (float4*)(attn + row * TK);
  o4[tid] = make_float4(e0 * inv, e1 * inv, e2 * inv, e3 * inv);
  o4[tid + 256] = make_float4(e4 * inv, e5 * inv, e6 * inv, e7 * inv);
}

// ---------------------------------------------------------------------------
// K4: context partials. grid (32 kc, 8 b, 2 qhalf): 512 blocks, 2/CU.
// part[b][kc][q][d] = sum_{k in chunk} attn[b][q][k]*keys[b][k][d]
// ---------------------------------------------------------------------------
__global__ __launch_bounds__(256) void ctx_partial(const float* __restrict__ keys,
                                                   const float* __restrict__ attn,
                                                   float* __restrict__ part) {
  const int b = blockIdx.y, kc = blockIdx.x, q0 = blockIdx.z * 16;
  const int d = threadIdx.x;
  const int kbase = kc * 64;
  float kv[64];
#pragma unroll
  for (int k = 0; k < 64; ++k)
    kv[k] = keys[(b * TK + kbase + k) * 256 + d];
  float* pout = part + (b * 32 + kc) * 8192 + q0 * 256 + d;
#pragma unroll 1
  for (int q = 0; q < 16; ++q) {
    const float4* ar = (const float4*)(attn + (b * TQ + q0 + q) * TK + kbase);  // uniform
    float a0 = 0.f, a1 = 0.f, a2 = 0.f, a3 = 0.f;
#pragma unroll
    for (int k4 = 0; k4 < 16; ++k4) {
      float4 av = ar[k4];
      a0 = fmaf(av.x, kv[k4 * 4 + 0], a0);
      a1 = fmaf(av.y, kv[k4 * 4 + 1], a1);
      a2 = fmaf(av.z, kv[k4 * 4 + 2], a2);
      a3 = fmaf(av.w, kv[k4 * 4 + 3], a3);
    }
    pout[q * 256] = (a0 + a1) + (a2 + a3);
  }
}

// ---------------------------------------------------------------------------
// K5: reduce partials over 32 kchunks -> context
// ---------------------------------------------------------------------------
__global__ __launch_bounds__(256) void ctx_reduce(const float* __restrict__ part,
                                                  float* __restrict__ ctx) {
  const int o = blockIdx.x * 256 + threadIdx.x;  // [b][q][d]
  const int b = o >> 13, qd = o & 8191;
  const float* p = part + b * 32 * 8192 + qd;
  float a0 = 0.f, a1 = 0.f, a2 = 0.f, a3 = 0.f;
#pragma unroll
  for (int kc = 0; kc < 8; ++kc) {
    a0 += p[(kc * 4 + 0) * 8192];
    a1 += p[(kc * 4 + 1) * 8192];
    a2 += p[(kc * 4 + 2) * 8192];
    a3 += p[(kc * 4 + 3) * 8192];
  }
  ctx[o] = (a0 + a1) + (a2 + a3);
}

extern "C" void kernel_launch(void* const* d_in, const int* in_sizes, int n_in,
                              void* d_out, int out_size, void* d_ws, size_t ws_size,
                              hipStream_t stream) {
  const float* query = (const float*)d_in[0];  // [8][32][256]
  const float* keys  = (const float*)d_in[1];  // [8][2048][256]
  const float* Wq    = (const float*)d_in[2];  // [256][256]
  const float* Wk    = (const float*)d_in[3];  // [256][256]
  const float* v     = (const float*)d_in[4];  // [256]

  float* out  = (float*)d_out;
  float* ctx  = out;           // 65536 floats: context [8][32][256]
  float* attn = out + 65536;   // 524288 floats: attn [8][32][2048]

  float* ws   = (float*)d_ws;
  float* kp   = ws;                  // 4194304 f
  float* qp   = ws + 4194304;        // 65536 f
  float* sc   = ws + 4259840;        // 524288 f
  float* part = ws + 4784128;        // 2097152 f
  u16* u   = (u16*)(ws + 6881280);
  u16* wkh = u;                      // 65536 u16 each
  u16* wkl = wkh + 65536;
  u16* wqh = wkl + 65536;
  u16* wql = wqh + 65536;

  convert_kernel<<<64, 256, 0, stream>>>(Wk, Wq, wkh, wkl, wqh, wql);
  proj_fused<<<260, 512, 0, stream>>>(keys, query, wkh, wkl, wqh, wql, kp, qp);
  score_kernel<<<dim3(32, 8), 1024, 0, stream>>>(kp, qp, v, sc);
  softmax_kernel<<<256, 256, 0, stream>>>(sc, attn);
  ctx_partial<<<dim3(32, 8, 2), 256, 0, stream>>>(keys, attn, part);
  ctx_reduce<<<256, 256, 0, stream>>>(part, ctx);
}

// Round 6
// 66.672 us; speedup vs baseline: 1.9086x; 1.1394x over previous
//
#include <hip/hip_runtime.h>
#include <hip/hip_bf16.h>

#define SCALE_2LOG2E 2.8853900817779268f   // 2*log2(e): folded into projections
#define LOG2E 1.4426950408889634f

#define NB 8
#define TQ 32
#define TK 2048
#define DD 256

typedef unsigned short u16;
typedef u16 u16x8 __attribute__((ext_vector_type(8)));
typedef __bf16 bf16x8 __attribute__((ext_vector_type(8)));
typedef float f32x4 __attribute__((ext_vector_type(4)));

// bf16 round-to-nearest-even split helpers (bit math: no header-type aliasing)
__device__ __forceinline__ u16 f2bf_u(float x) {
  unsigned int xi = __builtin_bit_cast(unsigned int, x);
  unsigned int r = (xi + 0x7fffu + ((xi >> 16) & 1u)) >> 16;
  return (u16)r;
}
__device__ __forceinline__ float bf2f(u16 u) {
  return __builtin_bit_cast(float, (unsigned int)u << 16);
}

// ---------------------------------------------------------------------------
// K0: fp32 -> bf16 hi/lo planes for Wk, Wq (64 blocks x 256 thr x 8 elems).
// ---------------------------------------------------------------------------
__global__ __launch_bounds__(256) void convert_kernel(
    const float* __restrict__ Wk, const float* __restrict__ Wq,
    u16* __restrict__ wkh, u16* __restrict__ wkl,
    u16* __restrict__ wqh, u16* __restrict__ wql) {
  const int bx = blockIdx.x;
  const float* src; u16 *dh, *dl; int base;
  if (bx < 32) { src = Wk; dh = wkh; dl = wkl; base = 0; }
  else         { src = Wq; dh = wqh; dl = wql; base = 32; }
  const int chunk = (bx - base) * 256 + threadIdx.x;   // 8-element chunk
  const float4* s4 = (const float4*)(src + chunk * 8);
  float4 x0 = s4[0], x1 = s4[1];
  const float xs[8] = {x0.x, x0.y, x0.z, x0.w, x1.x, x1.y, x1.z, x1.w};
  u16x8 h, l;
#pragma unroll
  for (int i = 0; i < 8; ++i) {
    u16 hh = f2bf_u(xs[i]);
    h[i] = hh;
    l[i] = f2bf_u(xs[i] - bf2f(hh));
  }
  *(u16x8*)(dh + chunk * 8) = h;
  *(u16x8*)(dl + chunk * 8) = l;
}

// ---------------------------------------------------------------------------
// K1: fused convert+GEMM (validated R4). C[m][u] = SCALE * sum_d A[m][d]*W[u][d].
// Tile 64(m) x 256(n). 512 thr = 8 waves, wave = 32x64 output. BK=64.
// ---------------------------------------------------------------------------
__global__ __launch_bounds__(512) void proj_fused(
    const float* __restrict__ keys, const float* __restrict__ query,
    const u16* __restrict__ wkh, const u16* __restrict__ wkl,
    const u16* __restrict__ wqh, const u16* __restrict__ wql,
    float* __restrict__ kpo, float* __restrict__ qpo) {
  __shared__ u16 Ah[64 * 64], Al[64 * 64];
  __shared__ u16 Bh[256 * 64], Bl[256 * 64];
  const int tid = threadIdx.x, lane = tid & 63, wv = tid >> 6;
  const int bx = blockIdx.x;
  const float* A; const u16 *bhg, *blg; float* C; int m0;
  if (bx < 256) { A = keys;  bhg = wkh; blg = wkl; C = kpo; m0 = bx * 64; }
  else          { A = query; bhg = wqh; blg = wql; C = qpo; m0 = (bx - 256) * 64; }
  const int wr = (wv >> 2) * 32, wc = (wv & 3) * 64;

  const int arow = tid >> 3, ac = tid & 7;             // A: row 0..63, chunk 0..7
  const float* ag = A + (m0 + arow) * 256 + ac * 8;
  const int aoff = arow * 64 + ((ac ^ (arow & 7)) << 3);

  f32x4 acc[2][4];
#pragma unroll
  for (int i = 0; i < 2; ++i)
#pragma unroll
    for (int j = 0; j < 4; ++j) acc[i][j] = {0.f, 0.f, 0.f, 0.f};

  for (int ks = 0; ks < 4; ++ks) {
    const int k0 = ks * 64;
    float4 a0 = *(const float4*)(ag + k0);
    float4 a1 = *(const float4*)(ag + k0 + 4);
    u16x8 sbh[4], sbl[4];
    int boff[4];
#pragma unroll
    for (int j = 0; j < 4; ++j) {
      int idx = tid + j * 512;                          // 0..2047
      int row = idx >> 3, c = idx & 7;
      sbh[j] = *(const u16x8*)(bhg + row * 256 + k0 + c * 8);
      sbl[j] = *(const u16x8*)(blg + row * 256 + k0 + c * 8);
      boff[j] = row * 64 + ((c ^ (row & 7)) << 3);
    }
    const float as[8] = {a0.x, a0.y, a0.z, a0.w, a1.x, a1.y, a1.z, a1.w};
    u16x8 hA, lA;
#pragma unroll
    for (int i = 0; i < 8; ++i) {
      u16 hh = f2bf_u(as[i]);
      hA[i] = hh;
      lA[i] = f2bf_u(as[i] - bf2f(hh));
    }
    if (ks) __syncthreads();                            // prev-step reads done
    *(u16x8*)&Ah[aoff] = hA;
    *(u16x8*)&Al[aoff] = lA;
#pragma unroll
    for (int j = 0; j < 4; ++j) {
      *(u16x8*)&Bh[boff[j]] = sbh[j];
      *(u16x8*)&Bl[boff[j]] = sbl[j];
    }
    __syncthreads();                                    // writes visible
#pragma unroll
    for (int s = 0; s < 2; ++s) {                       // ksub: 32 k each
      const int kc = s * 4 + (lane >> 4);               // 16B chunk in row
      bf16x8 fa[2][2], fb[4][2];                        // [frag][hi/lo]
#pragma unroll
      for (int mh = 0; mh < 2; ++mh) {
        int ra = wr + mh * 16 + (lane & 15);
        int off = ra * 64 + ((kc ^ (ra & 7)) << 3);
        fa[mh][0] = __builtin_bit_cast(bf16x8, *(const u16x8*)&Ah[off]);
        fa[mh][1] = __builtin_bit_cast(bf16x8, *(const u16x8*)&Al[off]);
      }
#pragma unroll
      for (int nh = 0; nh < 4; ++nh) {
        int rb = wc + nh * 16 + (lane & 15);
        int off = rb * 64 + ((kc ^ (rb & 7)) << 3);
        fb[nh][0] = __builtin_bit_cast(bf16x8, *(const u16x8*)&Bh[off]);
        fb[nh][1] = __builtin_bit_cast(bf16x8, *(const u16x8*)&Bl[off]);
      }
#pragma unroll
      for (int mh = 0; mh < 2; ++mh)
#pragma unroll
        for (int nh = 0; nh < 4; ++nh) {
          acc[mh][nh] = __builtin_amdgcn_mfma_f32_16x16x32_bf16(fa[mh][0], fb[nh][0], acc[mh][nh], 0, 0, 0);
          acc[mh][nh] = __builtin_amdgcn_mfma_f32_16x16x32_bf16(fa[mh][0], fb[nh][1], acc[mh][nh], 0, 0, 0);
          acc[mh][nh] = __builtin_amdgcn_mfma_f32_16x16x32_bf16(fa[mh][1], fb[nh][0], acc[mh][nh], 0, 0, 0);
        }
    }
  }
  // C/D layout (m89-verified): col = lane&15, row = (lane>>4)*4 + reg
#pragma unroll
  for (int mh = 0; mh < 2; ++mh)
#pragma unroll
    for (int nh = 0; nh < 4; ++nh)
#pragma unroll
      for (int j = 0; j < 4; ++j) {
        int row = m0 + wr + mh * 16 + (lane >> 4) * 4 + j;
        int col = wc + nh * 16 + (lane & 15);
        C[row * 256 + col] = acc[mh][nh][j] * SCALE_2LOG2E;
      }
}

// ---------------------------------------------------------------------------
// K2: fused score + chunk-local softmax stats + fp32 PV partial.
// grid (32 kc, 8 b), 1024 thr (16 waves, 4/SIMD). Wave w: q rows {2w,2w+1}.
// LDS 128KB: kp chunk (swizzled, 64KB) + keys chunk (linear, 64KB).
// Outputs: sc raw scores, pmax/psum[row][kc], part[b][kc][q][d].
// ---------------------------------------------------------------------------
__global__ __launch_bounds__(1024) void score_ctx_kernel(
    const float* __restrict__ kproj, const float* __restrict__ qproj,
    const float* __restrict__ v, const float* __restrict__ keys,
    float* __restrict__ sc, float* __restrict__ part,
    float* __restrict__ pmaxg, float* __restrict__ psumg) {
  __shared__ float kp[64 * 256];       // 64 KB, XOR-swizzled
  __shared__ float kbuf[64 * 256];     // 64 KB, linear [k][d]
  const int tid = threadIdx.x;
  const int b = blockIdx.y;
  const int kc = blockIdx.x;
  const int kbase = kc * 64;
#pragma unroll
  for (int i = 0; i < 4; ++i) {
    int idx4 = tid + i * 1024;         // 0..4095 float4s
    int kk = idx4 >> 6, u4 = idx4 & 63;
    float4 t = *(const float4*)(kproj + (b * TK + kbase + kk) * 256 + u4 * 4);
    *(float4*)&kp[kk * 256 + ((u4 ^ (kk & 7)) << 2)] = t;
    float4 kv = *(const float4*)(keys + (b * TK + kbase + kk) * 256 + u4 * 4);
    *(float4*)&kbuf[kk * 256 + u4 * 4] = kv;
  }
  const int lane = tid & 63;
  float vs = (v[lane] + v[lane + 64]) + (v[lane + 128] + v[lane + 192]);
#pragma unroll
  for (int off = 32; off; off >>= 1) vs += __shfl_xor(vs, off, 64);
  __syncthreads();

  const int wv = tid >> 6;             // 0..15, q rows {2wv, 2wv+1}
  const int xorv = lane & 7;
  const float* qr0 = qproj + (b * TQ + wv * 2) * 256;
  const float* qr1 = qr0 + 256;
  float sc0 = 0.f, sc1 = 0.f;
#pragma unroll 4
  for (int u4 = 0; u4 < 64; ++u4) {
    float4 kpv = *(const float4*)&kp[lane * 256 + ((u4 ^ xorv) << 2)];
    float4 qa = *(const float4*)(qr0 + u4 * 4);   // uniform -> s_load
    float4 qb = *(const float4*)(qr1 + u4 * 4);   // uniform -> s_load
    float4 vv = *(const float4*)(v + u4 * 4);     // uniform -> s_load
    sc0 = fmaf(vv.x, __builtin_amdgcn_rcpf(__builtin_amdgcn_exp2f(kpv.x + qa.x) + 1.f), sc0);
    sc1 = fmaf(vv.x, __builtin_amdgcn_rcpf(__builtin_amdgcn_exp2f(kpv.x + qb.x) + 1.f), sc1);
    sc0 = fmaf(vv.y, __builtin_amdgcn_rcpf(__builtin_amdgcn_exp2f(kpv.y + qa.y) + 1.f), sc0);
    sc1 = fmaf(vv.y, __builtin_amdgcn_rcpf(__builtin_amdgcn_exp2f(kpv.y + qb.y) + 1.f), sc1);
    sc0 = fmaf(vv.z, __builtin_amdgcn_rcpf(__builtin_amdgcn_exp2f(kpv.z + qa.z) + 1.f), sc0);
    sc1 = fmaf(vv.z, __builtin_amdgcn_rcpf(__builtin_amdgcn_exp2f(kpv.z + qb.z) + 1.f), sc1);
    sc0 = fmaf(vv.w, __builtin_amdgcn_rcpf(__builtin_amdgcn_exp2f(kpv.w + qa.w) + 1.f), sc0);
    sc1 = fmaf(vv.w, __builtin_amdgcn_rcpf(__builtin_amdgcn_exp2f(kpv.w + qb.w) + 1.f), sc1);
  }
  sc0 = fmaf(-2.f, sc0, vs);
  sc1 = fmaf(-2.f, sc1, vs);
  const int row0 = b * TQ + wv * 2;
  float* srow = sc + row0 * TK + kbase + lane;
  srow[0]  = sc0;
  srow[TK] = sc1;

  // chunk-local softmax stats (per row over 64 lanes)
  float m0 = sc0, m1 = sc1;
#pragma unroll
  for (int off = 32; off; off >>= 1) {
    m0 = fmaxf(m0, __shfl_xor(m0, off, 64));
    m1 = fmaxf(m1, __shfl_xor(m1, off, 64));
  }
  float p0 = __builtin_amdgcn_exp2f((sc0 - m0) * LOG2E);
  float p1 = __builtin_amdgcn_exp2f((sc1 - m1) * LOG2E);
  float l0 = p0, l1 = p1;
#pragma unroll
  for (int off = 32; off; off >>= 1) {
    l0 += __shfl_xor(l0, off, 64);
    l1 += __shfl_xor(l1, off, 64);
  }
  if (lane == 0) {
    pmaxg[row0 * 32 + kc] = m0;
    pmaxg[(row0 + 1) * 32 + kc] = m1;
    psumg[row0 * 32 + kc] = l0;
    psumg[(row0 + 1) * 32 + kc] = l1;
  }

  // PV: o[2 rows][256 d] partial = sum_k p[k] * keys[k][d]; lane = d-float4
  float4 o0 = {0.f, 0.f, 0.f, 0.f}, o1 = {0.f, 0.f, 0.f, 0.f};
  const int ip0 = __builtin_bit_cast(int, p0);
  const int ip1 = __builtin_bit_cast(int, p1);
#pragma unroll 8
  for (int k = 0; k < 64; ++k) {
    float4 kv = *(const float4*)&kbuf[k * 256 + lane * 4];
    float pk0 = __builtin_bit_cast(float, __builtin_amdgcn_readlane(ip0, k));
    float pk1 = __builtin_bit_cast(float, __builtin_amdgcn_readlane(ip1, k));
    o0.x = fmaf(pk0, kv.x, o0.x); o0.y = fmaf(pk0, kv.y, o0.y);
    o0.z = fmaf(pk0, kv.z, o0.z); o0.w = fmaf(pk0, kv.w, o0.w);
    o1.x = fmaf(pk1, kv.x, o1.x); o1.y = fmaf(pk1, kv.y, o1.y);
    o1.z = fmaf(pk1, kv.z, o1.z); o1.w = fmaf(pk1, kv.w, o1.w);
  }
  float* prow = part + (b * 32 + kc) * 8192 + (wv * 2) * 256 + lane * 4;
  *(float4*)prow = o0;
  *(float4*)(prow + 256) = o1;
}

// ---------------------------------------------------------------------------
// K3: combine. One block per (b,q) row, 256 thr.
// ctx[row][d] = sum_kc w_kc*part[b][kc][q][d] / L;  attn = exp(s-M)/L.
// w_kc = exp(pmax_kc - M), M = max_kc pmax, L = sum_kc w_kc*psum_kc.
// ---------------------------------------------------------------------------
__global__ __launch_bounds__(256) void combine_kernel(
    const float* __restrict__ part, const float* __restrict__ sc,
    const float* __restrict__ pmaxg, const float* __restrict__ psumg,
    float* __restrict__ ctx, float* __restrict__ attn) {
  const int row = blockIdx.x;          // b*32 + q
  const int b = row >> 5, q = row & 31;
  const int tid = threadIdx.x;
  __shared__ float wls[32];
  __shared__ float sM, sInvL;
  if (tid < 64) {
    const int lane = tid;
    float x = (lane < 32) ? pmaxg[row * 32 + lane] : -3.0e38f;
    float ps = (lane < 32) ? psumg[row * 32 + lane] : 0.f;
    float M = x;
#pragma unroll
    for (int off = 32; off; off >>= 1) M = fmaxf(M, __shfl_xor(M, off, 64));
    float w = (lane < 32) ? __builtin_amdgcn_exp2f((x - M) * LOG2E) : 0.f;
    float L = w * ps;
#pragma unroll
    for (int off = 32; off; off >>= 1) L += __shfl_xor(L, off, 64);
    if (lane < 32) wls[lane] = w;
    if (lane == 0) { sM = M; sInvL = __builtin_amdgcn_rcpf(L); }
  }
  __syncthreads();
  const float M = sM, invL = sInvL;
  // context: thread = d
  const float* p = part + b * 32 * 8192 + q * 256 + tid;
  float s = 0.f;
#pragma unroll
  for (int kc = 0; kc < 32; ++kc)
    s += wls[kc] * p[kc * 8192];
  ctx[row * 256 + tid] = s * invL;
  // attn: 8 elems/thread
  const float4* s4 = (const float4*)(sc + row * TK);
  float4 x0 = s4[tid], x1 = s4[tid + 256];
  float4* a4 = (float4*)(attn + row * TK);
  a4[tid] = make_float4(__builtin_amdgcn_exp2f((x0.x - M) * LOG2E) * invL,
                        __builtin_amdgcn_exp2f((x0.y - M) * LOG2E) * invL,
                        __builtin_amdgcn_exp2f((x0.z - M) * LOG2E) * invL,
                        __builtin_amdgcn_exp2f((x0.w - M) * LOG2E) * invL);
  a4[tid + 256] = make_float4(__builtin_amdgcn_exp2f((x1.x - M) * LOG2E) * invL,
                              __builtin_amdgcn_exp2f((x1.y - M) * LOG2E) * invL,
                              __builtin_amdgcn_exp2f((x1.z - M) * LOG2E) * invL,
                              __builtin_amdgcn_exp2f((x1.w - M) * LOG2E) * invL);
}

extern "C" void kernel_launch(void* const* d_in, const int* in_sizes, int n_in,
                              void* d_out, int out_size, void* d_ws, size_t ws_size,
                              hipStream_t stream) {
  const float* query = (const float*)d_in[0];  // [8][32][256]
  const float* keys  = (const float*)d_in[1];  // [8][2048][256]
  const float* Wq    = (const float*)d_in[2];  // [256][256]
  const float* Wk    = (const float*)d_in[3];  // [256][256]
  const float* v     = (const float*)d_in[4];  // [256]

  float* out  = (float*)d_out;
  float* ctx  = out;           // 65536 floats: context [8][32][256]
  float* attn = out + 65536;   // 524288 floats: attn [8][32][2048]

  float* ws   = (float*)d_ws;
  float* kp   = ws;                  // 4194304 f
  float* qp   = ws + 4194304;        // 65536 f
  float* sc   = ws + 4259840;        // 524288 f
  float* part = ws + 4784128;        // 2097152 f
  float* pmax = ws + 6881280;        // 8192 f
  float* psum = ws + 6889472;        // 8192 f
  u16* u   = (u16*)(ws + 6897664);
  u16* wkh = u;                      // 65536 u16 each
  u16* wkl = wkh + 65536;
  u16* wqh = wkl + 65536;
  u16* wql = wqh + 65536;

  convert_kernel<<<64, 256, 0, stream>>>(Wk, Wq, wkh, wkl, wqh, wql);
  proj_fused<<<260, 512, 0, stream>>>(keys, query, wkh, wkl, wqh, wql, kp, qp);
  score_ctx_kernel<<<dim3(32, 8), 1024, 0, stream>>>(kp, qp, v, keys, sc, part, pmax, psum);
  combine_kernel<<<256, 256, 0, stream>>>(part, sc, pmax, psum, ctx, attn);
}

// Round 7
// 65.347 us; speedup vs baseline: 1.9472x; 1.0203x over previous
//
#include <hip/hip_runtime.h>
#include <hip/hip_bf16.h>

#define SCALE_2LOG2E 2.8853900817779268f   // 2*log2(e): folded into projections
#define LOG2E 1.4426950408889634f

#define NB 8
#define TQ 32
#define TK 2048
#define DD 256

typedef unsigned short u16;
typedef u16 u16x8 __attribute__((ext_vector_type(8)));
typedef __bf16 bf16x8 __attribute__((ext_vector_type(8)));
typedef float f32x4 __attribute__((ext_vector_type(4)));

// bf16 round-to-nearest-even split helpers (bit math: no header-type aliasing)
__device__ __forceinline__ u16 f2bf_u(float x) {
  unsigned int xi = __builtin_bit_cast(unsigned int, x);
  unsigned int r = (xi + 0x7fffu + ((xi >> 16) & 1u)) >> 16;
  return (u16)r;
}
__device__ __forceinline__ float bf2f(u16 u) {
  return __builtin_bit_cast(float, (unsigned int)u << 16);
}

// ---------------------------------------------------------------------------
// K0: fp32 -> bf16 hi/lo planes for Wk, Wq (64 blocks x 256 thr x 8 elems).
// ---------------------------------------------------------------------------
__global__ __launch_bounds__(256) void convert_kernel(
    const float* __restrict__ Wk, const float* __restrict__ Wq,
    u16* __restrict__ wkh, u16* __restrict__ wkl,
    u16* __restrict__ wqh, u16* __restrict__ wql) {
  const int bx = blockIdx.x;
  const float* src; u16 *dh, *dl; int base;
  if (bx < 32) { src = Wk; dh = wkh; dl = wkl; base = 0; }
  else         { src = Wq; dh = wqh; dl = wql; base = 32; }
  const int chunk = (bx - base) * 256 + threadIdx.x;   // 8-element chunk
  const float4* s4 = (const float4*)(src + chunk * 8);
  float4 x0 = s4[0], x1 = s4[1];
  const float xs[8] = {x0.x, x0.y, x0.z, x0.w, x1.x, x1.y, x1.z, x1.w};
  u16x8 h, l;
#pragma unroll
  for (int i = 0; i < 8; ++i) {
    u16 hh = f2bf_u(xs[i]);
    h[i] = hh;
    l[i] = f2bf_u(xs[i] - bf2f(hh));
  }
  *(u16x8*)(dh + chunk * 8) = h;
  *(u16x8*)(dl + chunk * 8) = l;
}

// ---------------------------------------------------------------------------
// K1: fused convert+GEMM (validated R4). C[m][u] = SCALE * sum_d A[m][d]*W[u][d].
// Tile 64(m) x 256(n). 512 thr = 8 waves, wave = 32x64 output. BK=64.
// ---------------------------------------------------------------------------
__global__ __launch_bounds__(512) void proj_fused(
    const float* __restrict__ keys, const float* __restrict__ query,
    const u16* __restrict__ wkh, const u16* __restrict__ wkl,
    const u16* __restrict__ wqh, const u16* __restrict__ wql,
    float* __restrict__ kpo, float* __restrict__ qpo) {
  __shared__ u16 Ah[64 * 64], Al[64 * 64];
  __shared__ u16 Bh[256 * 64], Bl[256 * 64];
  const int tid = threadIdx.x, lane = tid & 63, wv = tid >> 6;
  const int bx = blockIdx.x;
  const float* A; const u16 *bhg, *blg; float* C; int m0;
  if (bx < 256) { A = keys;  bhg = wkh; blg = wkl; C = kpo; m0 = bx * 64; }
  else          { A = query; bhg = wqh; blg = wql; C = qpo; m0 = (bx - 256) * 64; }
  const int wr = (wv >> 2) * 32, wc = (wv & 3) * 64;

  const int arow = tid >> 3, ac = tid & 7;             // A: row 0..63, chunk 0..7
  const float* ag = A + (m0 + arow) * 256 + ac * 8;
  const int aoff = arow * 64 + ((ac ^ (arow & 7)) << 3);

  f32x4 acc[2][4];
#pragma unroll
  for (int i = 0; i < 2; ++i)
#pragma unroll
    for (int j = 0; j < 4; ++j) acc[i][j] = {0.f, 0.f, 0.f, 0.f};

  for (int ks = 0; ks < 4; ++ks) {
    const int k0 = ks * 64;
    float4 a0 = *(const float4*)(ag + k0);
    float4 a1 = *(const float4*)(ag + k0 + 4);
    u16x8 sbh[4], sbl[4];
    int boff[4];
#pragma unroll
    for (int j = 0; j < 4; ++j) {
      int idx = tid + j * 512;                          // 0..2047
      int row = idx >> 3, c = idx & 7;
      sbh[j] = *(const u16x8*)(bhg + row * 256 + k0 + c * 8);
      sbl[j] = *(const u16x8*)(blg + row * 256 + k0 + c * 8);
      boff[j] = row * 64 + ((c ^ (row & 7)) << 3);
    }
    const float as[8] = {a0.x, a0.y, a0.z, a0.w, a1.x, a1.y, a1.z, a1.w};
    u16x8 hA, lA;
#pragma unroll
    for (int i = 0; i < 8; ++i) {
      u16 hh = f2bf_u(as[i]);
      hA[i] = hh;
      lA[i] = f2bf_u(as[i] - bf2f(hh));
    }
    if (ks) __syncthreads();                            // prev-step reads done
    *(u16x8*)&Ah[aoff] = hA;
    *(u16x8*)&Al[aoff] = lA;
#pragma unroll
    for (int j = 0; j < 4; ++j) {
      *(u16x8*)&Bh[boff[j]] = sbh[j];
      *(u16x8*)&Bl[boff[j]] = sbl[j];
    }
    __syncthreads();                                    // writes visible
#pragma unroll
    for (int s = 0; s < 2; ++s) {                       // ksub: 32 k each
      const int kc = s * 4 + (lane >> 4);               // 16B chunk in row
      bf16x8 fa[2][2], fb[4][2];                        // [frag][hi/lo]
#pragma unroll
      for (int mh = 0; mh < 2; ++mh) {
        int ra = wr + mh * 16 + (lane & 15);
        int off = ra * 64 + ((kc ^ (ra & 7)) << 3);
        fa[mh][0] = __builtin_bit_cast(bf16x8, *(const u16x8*)&Ah[off]);
        fa[mh][1] = __builtin_bit_cast(bf16x8, *(const u16x8*)&Al[off]);
      }
#pragma unroll
      for (int nh = 0; nh < 4; ++nh) {
        int rb = wc + nh * 16 + (lane & 15);
        int off = rb * 64 + ((kc ^ (rb & 7)) << 3);
        fb[nh][0] = __builtin_bit_cast(bf16x8, *(const u16x8*)&Bh[off]);
        fb[nh][1] = __builtin_bit_cast(bf16x8, *(const u16x8*)&Bl[off]);
      }
#pragma unroll
      for (int mh = 0; mh < 2; ++mh)
#pragma unroll
        for (int nh = 0; nh < 4; ++nh) {
          acc[mh][nh] = __builtin_amdgcn_mfma_f32_16x16x32_bf16(fa[mh][0], fb[nh][0], acc[mh][nh], 0, 0, 0);
          acc[mh][nh] = __builtin_amdgcn_mfma_f32_16x16x32_bf16(fa[mh][0], fb[nh][1], acc[mh][nh], 0, 0, 0);
          acc[mh][nh] = __builtin_amdgcn_mfma_f32_16x16x32_bf16(fa[mh][1], fb[nh][0], acc[mh][nh], 0, 0, 0);
        }
    }
  }
  // C/D layout (m89-verified): col = lane&15, row = (lane>>4)*4 + reg
#pragma unroll
  for (int mh = 0; mh < 2; ++mh)
#pragma unroll
    for (int nh = 0; nh < 4; ++nh)
#pragma unroll
      for (int j = 0; j < 4; ++j) {
        int row = m0 + wr + mh * 16 + (lane >> 4) * 4 + j;
        int col = wc + nh * 16 + (lane & 15);
        C[row * 256 + col] = acc[mh][nh][j] * SCALE_2LOG2E;
      }
}

// ---------------------------------------------------------------------------
// K2: fused score + chunk-local softmax stats + fp32 PV partial.
// grid (32 kc, 8 b), 1024 thr (16 waves). Wave w: q rows {2w,2w+1}.
// LDS 64KB (kp chunk only) -> 2 blocks/CU, 32 waves/CU.
// PV reads keys rows straight from global (coalesced 1KB/row, L2-resident).
// Outputs: sc raw scores, pmax/psum[row][kc], part[b][kc][q][d].
// ---------------------------------------------------------------------------
__global__ __launch_bounds__(1024) void score_ctx_kernel(
    const float* __restrict__ kproj, const float* __restrict__ qproj,
    const float* __restrict__ v, const float* __restrict__ keys,
    float* __restrict__ sc, float* __restrict__ part,
    float* __restrict__ pmaxg, float* __restrict__ psumg) {
  __shared__ float kp[64 * 256];       // 64 KB, XOR-swizzled
  const int tid = threadIdx.x;
  const int b = blockIdx.y;
  const int kc = blockIdx.x;
  const int kbase = kc * 64;
#pragma unroll
  for (int i = 0; i < 4; ++i) {
    int idx4 = tid + i * 1024;         // 0..4095 float4s
    int kk = idx4 >> 6, u4 = idx4 & 63;
    float4 t = *(const float4*)(kproj + (b * TK + kbase + kk) * 256 + u4 * 4);
    *(float4*)&kp[kk * 256 + ((u4 ^ (kk & 7)) << 2)] = t;
  }
  const int lane = tid & 63;
  float vs = (v[lane] + v[lane + 64]) + (v[lane + 128] + v[lane + 192]);
#pragma unroll
  for (int off = 32; off; off >>= 1) vs += __shfl_xor(vs, off, 64);
  __syncthreads();

  const int wv = tid >> 6;             // 0..15, q rows {2wv, 2wv+1}
  const int xorv = lane & 7;
  const float* qr0 = qproj + (b * TQ + wv * 2) * 256;
  const float* qr1 = qr0 + 256;
  float sc0 = 0.f, sc1 = 0.f;
#pragma unroll 4
  for (int u4 = 0; u4 < 64; ++u4) {
    float4 kpv = *(const float4*)&kp[lane * 256 + ((u4 ^ xorv) << 2)];
    float4 qa = *(const float4*)(qr0 + u4 * 4);   // uniform -> s_load
    float4 qb = *(const float4*)(qr1 + u4 * 4);   // uniform -> s_load
    float4 vv = *(const float4*)(v + u4 * 4);     // uniform -> s_load
    sc0 = fmaf(vv.x, __builtin_amdgcn_rcpf(__builtin_amdgcn_exp2f(kpv.x + qa.x) + 1.f), sc0);
    sc1 = fmaf(vv.x, __builtin_amdgcn_rcpf(__builtin_amdgcn_exp2f(kpv.x + qb.x) + 1.f), sc1);
    sc0 = fmaf(vv.y, __builtin_amdgcn_rcpf(__builtin_amdgcn_exp2f(kpv.y + qa.y) + 1.f), sc0);
    sc1 = fmaf(vv.y, __builtin_amdgcn_rcpf(__builtin_amdgcn_exp2f(kpv.y + qb.y) + 1.f), sc1);
    sc0 = fmaf(vv.z, __builtin_amdgcn_rcpf(__builtin_amdgcn_exp2f(kpv.z + qa.z) + 1.f), sc0);
    sc1 = fmaf(vv.z, __builtin_amdgcn_rcpf(__builtin_amdgcn_exp2f(kpv.z + qb.z) + 1.f), sc1);
    sc0 = fmaf(vv.w, __builtin_amdgcn_rcpf(__builtin_amdgcn_exp2f(kpv.w + qa.w) + 1.f), sc0);
    sc1 = fmaf(vv.w, __builtin_amdgcn_rcpf(__builtin_amdgcn_exp2f(kpv.w + qb.w) + 1.f), sc1);
  }
  sc0 = fmaf(-2.f, sc0, vs);
  sc1 = fmaf(-2.f, sc1, vs);
  const int row0 = b * TQ + wv * 2;
  float* srow = sc + row0 * TK + kbase + lane;
  srow[0]  = sc0;
  srow[TK] = sc1;

  // chunk-local softmax stats (per row over 64 lanes)
  float m0 = sc0, m1 = sc1;
#pragma unroll
  for (int off = 32; off; off >>= 1) {
    m0 = fmaxf(m0, __shfl_xor(m0, off, 64));
    m1 = fmaxf(m1, __shfl_xor(m1, off, 64));
  }
  float p0 = __builtin_amdgcn_exp2f((sc0 - m0) * LOG2E);
  float p1 = __builtin_amdgcn_exp2f((sc1 - m1) * LOG2E);
  float l0 = p0, l1 = p1;
#pragma unroll
  for (int off = 32; off; off >>= 1) {
    l0 += __shfl_xor(l0, off, 64);
    l1 += __shfl_xor(l1, off, 64);
  }
  if (lane == 0) {
    pmaxg[row0 * 32 + kc] = m0;
    pmaxg[(row0 + 1) * 32 + kc] = m1;
    psumg[row0 * 32 + kc] = l0;
    psumg[(row0 + 1) * 32 + kc] = l1;
  }

  // PV: o[2 rows][256 d] partial = sum_k p[k]*keys[k][d]; lane = d-float4.
  // keys rows read from global: 1KB coalesced per row, L2-resident chunk.
  float4 o0 = {0.f, 0.f, 0.f, 0.f}, o1 = {0.f, 0.f, 0.f, 0.f};
  const int ip0 = __builtin_bit_cast(int, p0);
  const int ip1 = __builtin_bit_cast(int, p1);
  const float* krow = keys + (b * TK + kbase) * 256 + lane * 4;
#pragma unroll 8
  for (int k = 0; k < 64; ++k) {
    float4 kv = *(const float4*)(krow + k * 256);
    float pk0 = __builtin_bit_cast(float, __builtin_amdgcn_readlane(ip0, k));
    float pk1 = __builtin_bit_cast(float, __builtin_amdgcn_readlane(ip1, k));
    o0.x = fmaf(pk0, kv.x, o0.x); o0.y = fmaf(pk0, kv.y, o0.y);
    o0.z = fmaf(pk0, kv.z, o0.z); o0.w = fmaf(pk0, kv.w, o0.w);
    o1.x = fmaf(pk1, kv.x, o1.x); o1.y = fmaf(pk1, kv.y, o1.y);
    o1.z = fmaf(pk1, kv.z, o1.z); o1.w = fmaf(pk1, kv.w, o1.w);
  }
  float* prow = part + (b * 32 + kc) * 8192 + (wv * 2) * 256 + lane * 4;
  *(float4*)prow = o0;
  *(float4*)(prow + 256) = o1;
}

// ---------------------------------------------------------------------------
// K3: combine. One block per (b,q) row, 256 thr.
// ctx[row][d] = sum_kc w_kc*part[b][kc][q][d] / L;  attn = exp(s-M)/L.
// w_kc = exp(pmax_kc - M), M = max_kc pmax, L = sum_kc w_kc*psum_kc.
// ---------------------------------------------------------------------------
__global__ __launch_bounds__(256) void combine_kernel(
    const float* __restrict__ part, const float* __restrict__ sc,
    const float* __restrict__ pmaxg, const float* __restrict__ psumg,
    float* __restrict__ ctx, float* __restrict__ attn) {
  const int row = blockIdx.x;          // b*32 + q
  const int b = row >> 5, q = row & 31;
  const int tid = threadIdx.x;
  __shared__ float wls[32];
  __shared__ float sM, sInvL;
  if (tid < 64) {
    const int lane = tid;
    float x = (lane < 32) ? pmaxg[row * 32 + lane] : -3.0e38f;
    float ps = (lane < 32) ? psumg[row * 32 + lane] : 0.f;
    float M = x;
#pragma unroll
    for (int off = 32; off; off >>= 1) M = fmaxf(M, __shfl_xor(M, off, 64));
    float w = (lane < 32) ? __builtin_amdgcn_exp2f((x - M) * LOG2E) : 0.f;
    float L = w * ps;
#pragma unroll
    for (int off = 32; off; off >>= 1) L += __shfl_xor(L, off, 64);
    if (lane < 32) wls[lane] = w;
    if (lane == 0) { sM = M; sInvL = __builtin_amdgcn_rcpf(L); }
  }
  __syncthreads();
  const float M = sM, invL = sInvL;
  // context: thread = d
  const float* p = part + b * 32 * 8192 + q * 256 + tid;
  float s = 0.f;
#pragma unroll
  for (int kc = 0; kc < 32; ++kc)
    s += wls[kc] * p[kc * 8192];
  ctx[row * 256 + tid] = s * invL;
  // attn: 8 elems/thread
  const float4* s4 = (const float4*)(sc + row * TK);
  float4 x0 = s4[tid], x1 = s4[tid + 256];
  float4* a4 = (float4*)(attn + row * TK);
  a4[tid] = make_float4(__builtin_amdgcn_exp2f((x0.x - M) * LOG2E) * invL,
                        __builtin_amdgcn_exp2f((x0.y - M) * LOG2E) * invL,
                        __builtin_amdgcn_exp2f((x0.z - M) * LOG2E) * invL,
                        __builtin_amdgcn_exp2f((x0.w - M) * LOG2E) * invL);
  a4[tid + 256] = make_float4(__builtin_amdgcn_exp2f((x1.x - M) * LOG2E) * invL,
                              __builtin_amdgcn_exp2f((x1.y - M) * LOG2E) * invL,
                              __builtin_amdgcn_exp2f((x1.z - M) * LOG2E) * invL,
                              __builtin_amdgcn_exp2f((x1.w - M) * LOG2E) * invL);
}

extern "C" void kernel_launch(void* const* d_in, const int* in_sizes, int n_in,
                              void* d_out, int out_size, void* d_ws, size_t ws_size,
                              hipStream_t stream) {
  const float* query = (const float*)d_in[0];  // [8][32][256]
  const float* keys  = (const float*)d_in[1];  // [8][2048][256]
  const float* Wq    = (const float*)d_in[2];  // [256][256]
  const float* Wk    = (const float*)d_in[3];  // [256][256]
  const float* v     = (const float*)d_in[4];  // [256]

  float* out  = (float*)d_out;
  float* ctx  = out;           // 65536 floats: context [8][32][256]
  float* attn = out + 65536;   // 524288 floats: attn [8][32][2048]

  float* ws   = (float*)d_ws;
  float* kp   = ws;                  // 4194304 f
  float* qp   = ws + 4194304;        // 65536 f
  float* sc   = ws + 4259840;        // 524288 f
  float* part = ws + 4784128;        // 2097152 f
  float* pmax = ws + 6881280;        // 8192 f
  float* psum = ws + 6889472;        // 8192 f
  u16* u   = (u16*)(ws + 6897664);
  u16* wkh = u;                      // 65536 u16 each
  u16* wkl = wkh + 65536;
  u16* wqh = wkl + 65536;
  u16* wql = wqh + 65536;

  convert_kernel<<<64, 256, 0, stream>>>(Wk, Wq, wkh, wkl, wqh, wql);
  proj_fused<<<260, 512, 0, stream>>>(keys, query, wkh, wkl, wqh, wql, kp, qp);
  score_ctx_kernel<<<dim3(32, 8), 1024, 0, stream>>>(kp, qp, v, keys, sc, part, pmax, psum);
  combine_kernel<<<256, 256, 0, stream>>>(part, sc, pmax, psum, ctx, attn);
}